// Round 2
// baseline (8624.551 us; speedup 1.0000x reference)
//
#include <hip/hip_runtime.h>

// ---------------------------------------------------------------------------
// IGCN link prediction, f32 baseline.
// out[p] = a[idx0[p]] + b[idx1[p]] + c   (decoder is linear -> collapsed)
// ---------------------------------------------------------------------------

__device__ __forceinline__ float wave_sum64(float x) {
#pragma unroll
    for (int o = 32; o > 0; o >>= 1) x += __shfl_xor(x, o, 64);
    return x;
}

// S[nrows,C] = X[nrows,K] @ W[K,C].  W staged in LDS. 64 rows per block.
template <int K, int C>
__global__ __launch_bounds__(256) void gemm_k(const float* __restrict__ X,
                                              const float* __restrict__ W,
                                              float* __restrict__ S, int nrows) {
    constexpr int ROWS = 64;
    constexpr int CP4 = C / 4;        // col quads
    constexpr int RG = 256 / CP4;     // row groups
    constexpr int RPT = ROWS / RG;    // rows per thread
    __shared__ float WL[K * C];

    const int t = threadIdx.x;
    for (int i = t; i < K * C / 4; i += 256)
        ((float4*)WL)[i] = ((const float4*)W)[i];
    __syncthreads();

    const int row0 = blockIdx.x * ROWS;
    const int col4 = t % CP4;
    const int rg = t / CP4;
    const int rbase = row0 + rg * RPT;

    float4 acc[RPT];
#pragma unroll
    for (int r = 0; r < RPT; ++r) acc[r] = make_float4(0.f, 0.f, 0.f, 0.f);

#pragma unroll 4
    for (int k4 = 0; k4 < K / 4; ++k4) {
        float4 w0 = ((const float4*)WL)[(4 * k4 + 0) * CP4 + col4];
        float4 w1 = ((const float4*)WL)[(4 * k4 + 1) * CP4 + col4];
        float4 w2 = ((const float4*)WL)[(4 * k4 + 2) * CP4 + col4];
        float4 w3 = ((const float4*)WL)[(4 * k4 + 3) * CP4 + col4];
#pragma unroll
        for (int r = 0; r < RPT; ++r) {
            int gr = rbase + r;
            if (gr < nrows) {
                float4 xv = ((const float4*)X)[(size_t)gr * (K / 4) + k4];
                acc[r].x += xv.x * w0.x + xv.y * w1.x + xv.z * w2.x + xv.w * w3.x;
                acc[r].y += xv.x * w0.y + xv.y * w1.y + xv.z * w2.y + xv.w * w3.y;
                acc[r].z += xv.x * w0.z + xv.y * w1.z + xv.z * w2.z + xv.w * w3.z;
                acc[r].w += xv.x * w0.w + xv.y * w1.w + xv.z * w2.w + xv.w * w3.w;
            }
        }
    }
#pragma unroll
    for (int r = 0; r < RPT; ++r) {
        int gr = rbase + r;
        if (gr < nrows) ((float4*)S)[(size_t)gr * CP4 + col4] = acc[r];
    }
}

// A[dst] += S[src] * val  over edges; C/4 threads per edge, float4 per thread.
template <int C>
__global__ __launch_bounds__(256) void spmm_k(const int* __restrict__ edges,
                                              const float* __restrict__ vals,
                                              const float* __restrict__ S,
                                              float* __restrict__ A, int E) {
    constexpr int TPE = C / 4;
    int tid = blockIdx.x * 256 + threadIdx.x;
    int e = tid / TPE;
    if (e >= E) return;
    int f = tid & (TPE - 1);
    int dst = edges[e];
    int src = edges[E + e];
    float v = vals[e];
    float4 m = ((const float4*)S)[(size_t)src * TPE + f];
    float* out = A + (size_t)dst * C + (size_t)f * 4;
    atomicAdd(out + 0, m.x * v);
    atomicAdd(out + 1, m.y * v);
    atomicAdd(out + 2, m.z * v);
    atomicAdd(out + 3, m.w * v);
}

// A = relu(A + b) elementwise over [n, C], float4-vectorized, in place.
template <int C>
__global__ __launch_bounds__(256) void bias_relu_k(float* __restrict__ A,
                                                   const float* __restrict__ b,
                                                   int n4) {
    int i = blockIdx.x * 256 + threadIdx.x;
    if (i >= n4) return;
    int q = i % (C / 4);
    float4 x = ((float4*)A)[i];
    float4 bb = ((const float4*)b)[q];
    x.x = fmaxf(x.x + bb.x, 0.f);
    x.y = fmaxf(x.y + bb.y, 0.f);
    x.z = fmaxf(x.z + bb.z, 0.f);
    x.w = fmaxf(x.w + bb.w, 0.f);
    ((float4*)A)[i] = x;
}

// v[i] = sum_j dec1_W[i][j] * dec2_W[j];  c = dec1_b . dec2_W + dec2_b
__global__ void vc_k(const float* __restrict__ dec1_W, const float* __restrict__ dec1_b,
                     const float* __restrict__ dec2_W, const float* __restrict__ dec2_b,
                     float* __restrict__ v, float* __restrict__ c) {
    int i = threadIdx.x;  // 128 threads
    float s = 0.f;
    for (int j = 0; j < 64; ++j) s += dec1_W[i * 64 + j] * dec2_W[j];
    v[i] = s;
    if (i == 0) {
        float cc = 0.f;
        for (int j = 0; j < 64; ++j) cc += dec1_b[j] * dec2_W[j];
        *c = cc + dec2_b[0];
    }
}

// One wave per node: x1 = A2o+b_o2, x2 = A2s+b_s2 (NH2=64 lanes),
// g = (x1.ag1)*x1 + (x2.ag2)*x2 ; a[n]=g.v[0:64], b[n]=g.v[64:128]
__global__ __launch_bounds__(256) void gate_k(const float* __restrict__ A2o,
                                              const float* __restrict__ A2s,
                                              const float* __restrict__ b_o2,
                                              const float* __restrict__ b_s2,
                                              const float* __restrict__ ag1,
                                              const float* __restrict__ ag2,
                                              const float* __restrict__ v,
                                              float* __restrict__ a,
                                              float* __restrict__ b, int n) {
    int gt = blockIdx.x * 256 + threadIdx.x;
    int wid = gt >> 6;
    int lane = gt & 63;
    if (wid >= n) return;
    float x1 = A2o[(size_t)wid * 64 + lane] + b_o2[lane];
    float x2 = A2s[(size_t)wid * 64 + lane] + b_s2[lane];
    float d1 = wave_sum64(x1 * ag1[lane]);
    float d2 = wave_sum64(x2 * ag2[lane]);
    float g = d1 * x1 + d2 * x2;
    float av = wave_sum64(g * v[lane]);
    float bv = wave_sum64(g * v[64 + lane]);
    if (lane == 0) {
        a[wid] = av;
        b[wid] = bv;
    }
}

__global__ __launch_bounds__(256) void decode_k(const int* __restrict__ idx,
                                                const float* __restrict__ a,
                                                const float* __restrict__ b,
                                                const float* __restrict__ c,
                                                float* __restrict__ out, int P) {
    int i = blockIdx.x * 256 + threadIdx.x;
    if (i >= P) return;
    out[i] = a[idx[i]] + b[idx[P + i]] + *c;
}

extern "C" void kernel_launch(void* const* d_in, const int* in_sizes, int n_in,
                              void* d_out, int out_size, void* d_ws, size_t ws_size,
                              hipStream_t stream) {
    const float* x      = (const float*)d_in[0];
    const int*   o_edges= (const int*)d_in[1];
    const float* o_vals = (const float*)d_in[2];
    const int*   s_edges= (const int*)d_in[3];
    const float* s_vals = (const float*)d_in[4];
    const int*   idx    = (const int*)d_in[5];
    const float* W_o1   = (const float*)d_in[6];
    const float* b_o1   = (const float*)d_in[7];
    const float* W_o2   = (const float*)d_in[8];
    const float* b_o2   = (const float*)d_in[9];
    const float* W_s1   = (const float*)d_in[10];
    const float* b_s1   = (const float*)d_in[11];
    const float* W_s2   = (const float*)d_in[12];
    const float* b_s2   = (const float*)d_in[13];
    const float* ag1    = (const float*)d_in[14];
    const float* ag2    = (const float*)d_in[15];
    const float* dec1_W = (const float*)d_in[16];
    const float* dec1_b = (const float*)d_in[17];
    const float* dec2_W = (const float*)d_in[18];
    const float* dec2_b = (const float*)d_in[19];
    float* out = (float*)d_out;

    const int N = in_sizes[0] / 128;
    const int E = in_sizes[1] / 2;
    const int P = out_size;

    const size_t NB1 = (size_t)N * 128 * 4;  // bytes of an [N,128] f32 buffer
    const size_t NB2 = (size_t)N * 64 * 4;   // bytes of an [N,64] f32 buffer

    char* ws = (char*)d_ws;
    float* S1o = (float*)(ws + 0);
    float* S1s = (float*)(ws + NB1);
    float* A1o = (float*)(ws + 2 * NB1);
    float* A1s = (float*)(ws + 3 * NB1);
    // reuse dead regions for layer 2:
    float* S2o = (float*)(ws + 0);           // over S1o (dead after spmm1)
    float* S2s = (float*)(ws + NB2);         // still inside old S1o region
    float* A2o = (float*)(ws + NB1);         // over S1s (dead after spmm1)
    float* A2s = (float*)(ws + NB1 + NB2);
    float* av  = (float*)(ws + 4 * NB1);
    float* bv  = (float*)(ws + 4 * NB1 + (size_t)P * 4);
    float* vv  = (float*)(ws + 4 * NB1 + (size_t)P * 8);
    float* cc  = (float*)(ws + 4 * NB1 + (size_t)P * 8 + 512);

    // zero aggregation buffers for layer 1 (A1o,A1s contiguous)
    hipMemsetAsync(ws + 2 * NB1, 0, 2 * NB1, stream);

    vc_k<<<1, 128, 0, stream>>>(dec1_W, dec1_b, dec2_W, dec2_b, vv, cc);

    const int gblocks = (N + 63) / 64;
    gemm_k<128, 128><<<gblocks, 256, 0, stream>>>(x, W_o1, S1o, N);
    gemm_k<128, 128><<<gblocks, 256, 0, stream>>>(x, W_s1, S1s, N);

    const int sblocks1 = (E * 32 + 255) / 256;
    spmm_k<128><<<sblocks1, 256, 0, stream>>>(o_edges, o_vals, S1o, A1o, E);
    spmm_k<128><<<sblocks1, 256, 0, stream>>>(s_edges, s_vals, S1s, A1s, E);

    const int rblocks = (N * 32 + 255) / 256;  // N*128/4 quads
    bias_relu_k<128><<<rblocks, 256, 0, stream>>>(A1o, b_o1, N * 32);
    bias_relu_k<128><<<rblocks, 256, 0, stream>>>(A1s, b_s1, N * 32);

    gemm_k<128, 64><<<gblocks, 256, 0, stream>>>(A1o, W_o2, S2o, N);
    gemm_k<128, 64><<<gblocks, 256, 0, stream>>>(A1s, W_s2, S2s, N);

    // zero aggregation buffers for layer 2 (A2o,A2s contiguous at ws+NB1)
    hipMemsetAsync(ws + NB1, 0, 2 * NB2, stream);

    const int sblocks2 = (E * 16 + 255) / 256;
    spmm_k<64><<<sblocks2, 256, 0, stream>>>(o_edges, o_vals, S2o, A2o, E);
    spmm_k<64><<<sblocks2, 256, 0, stream>>>(s_edges, s_vals, S2s, A2s, E);

    const int wblocks = (N * 64 + 255) / 256;  // one wave per node
    gate_k<<<wblocks, 256, 0, stream>>>(A2o, A2s, b_o2, b_s2, ag1, ag2, vv, av, bv, N);

    decode_k<<<(P + 255) / 256, 256, 0, stream>>>(idx, av, bv, cc, out, P);
}

// Round 4
// 1453.906 us; speedup vs baseline: 5.9320x; 5.9320x over previous
//
#include <hip/hip_runtime.h>

// ---------------------------------------------------------------------------
// IGCN link prediction, round 3: R2 (CSR gather SpMM) + fix: the histogram
// count/cursor arrays are ONE contiguous 2N block so the memset covers both
// (R2 left 32 poisoned counters in wo_s -> OOB scatter -> crash).
// out[p] = a[idx0[p]] + b[idx1[p]] + c   (decoder is linear -> collapsed)
// ---------------------------------------------------------------------------

__device__ __forceinline__ float wave_sum64(float x) {
#pragma unroll
    for (int o = 32; o > 0; o >>= 1) x += __shfl_xor(x, o, 64);
    return x;
}

// ---------------- CSR construction ----------------

// count in-degree: cnt[dst]++
__global__ __launch_bounds__(256) void hist_k(const int* __restrict__ edges,
                                              int* __restrict__ cnt, int E) {
    int e = blockIdx.x * 256 + threadIdx.x;
    if (e >= E) return;
    atomicAdd(&cnt[edges[e]], 1);
}

// phase A: per-block exclusive scan (256 elems/block), block sums out
__global__ __launch_bounds__(256) void scan_a_k(const int* __restrict__ cnt,
                                                int* __restrict__ exc,
                                                int* __restrict__ bsum, int n) {
    __shared__ int sh[256];
    int tid = threadIdx.x;
    int i = blockIdx.x * 256 + tid;
    int v = (i < n) ? cnt[i] : 0;
    sh[tid] = v;
    __syncthreads();
#pragma unroll
    for (int o = 1; o < 256; o <<= 1) {
        int t = (tid >= o) ? sh[tid - o] : 0;
        __syncthreads();
        sh[tid] += t;
        __syncthreads();
    }
    if (i < n) exc[i] = sh[tid] - v;  // exclusive
    if (tid == 255) bsum[blockIdx.x] = sh[tid];
}

// phase B: exclusive scan of block sums (nblk <= 512), single block
__global__ __launch_bounds__(512) void scan_b_k(int* __restrict__ bsum, int nblk) {
    __shared__ int sh[512];
    int t = threadIdx.x;
    int v = (t < nblk) ? bsum[t] : 0;
    sh[t] = v;
    __syncthreads();
#pragma unroll
    for (int o = 1; o < 512; o <<= 1) {
        int tv = (t >= o) ? sh[t - o] : 0;
        __syncthreads();
        sh[t] += tv;
        __syncthreads();
    }
    if (t < nblk) bsum[t] = sh[t] - v;
}

// phase C: add block offsets -> row_ptr, copy to write cursors, set rp[n]=E
__global__ __launch_bounds__(256) void scan_c_k(int* __restrict__ rp,
                                                int* __restrict__ wo,
                                                const int* __restrict__ bsum,
                                                int n, int E) {
    int i = blockIdx.x * 256 + threadIdx.x;
    if (i < n) {
        int v = rp[i] + bsum[blockIdx.x];
        rp[i] = v;
        wo[i] = v;
    }
    if (i == 0) rp[n] = E;
}

// scatter edges into CSR buckets
__global__ __launch_bounds__(256) void scatter_k(const int* __restrict__ edges,
                                                 const float* __restrict__ vals,
                                                 int* __restrict__ wo,
                                                 int* __restrict__ csr_src,
                                                 float* __restrict__ csr_val, int E) {
    int e = blockIdx.x * 256 + threadIdx.x;
    if (e >= E) return;
    int dst = edges[e];
    int pos = atomicAdd(&wo[dst], 1);
    csr_src[pos] = edges[E + e];
    csr_val[pos] = vals[e];
}

// ---------------- dense GEMM: S[nrows,C] = X[nrows,K] @ W[K,C] ----------------

template <int K, int C>
__global__ __launch_bounds__(256) void gemm_k(const float* __restrict__ X,
                                              const float* __restrict__ W,
                                              float* __restrict__ S, int nrows) {
    constexpr int ROWS = 64;
    constexpr int CP4 = C / 4;
    constexpr int RG = 256 / CP4;
    constexpr int RPT = ROWS / RG;
    __shared__ float WL[K * C];

    const int t = threadIdx.x;
    for (int i = t; i < K * C / 4; i += 256)
        ((float4*)WL)[i] = ((const float4*)W)[i];
    __syncthreads();

    const int row0 = blockIdx.x * ROWS;
    const int col4 = t % CP4;
    const int rg = t / CP4;
    const int rbase = row0 + rg * RPT;

    float4 acc[RPT];
#pragma unroll
    for (int r = 0; r < RPT; ++r) acc[r] = make_float4(0.f, 0.f, 0.f, 0.f);

#pragma unroll 4
    for (int k4 = 0; k4 < K / 4; ++k4) {
        float4 w0 = ((const float4*)WL)[(4 * k4 + 0) * CP4 + col4];
        float4 w1 = ((const float4*)WL)[(4 * k4 + 1) * CP4 + col4];
        float4 w2 = ((const float4*)WL)[(4 * k4 + 2) * CP4 + col4];
        float4 w3 = ((const float4*)WL)[(4 * k4 + 3) * CP4 + col4];
#pragma unroll
        for (int r = 0; r < RPT; ++r) {
            int gr = rbase + r;
            if (gr < nrows) {
                float4 xv = ((const float4*)X)[(size_t)gr * (K / 4) + k4];
                acc[r].x += xv.x * w0.x + xv.y * w1.x + xv.z * w2.x + xv.w * w3.x;
                acc[r].y += xv.x * w0.y + xv.y * w1.y + xv.z * w2.y + xv.w * w3.y;
                acc[r].z += xv.x * w0.z + xv.y * w1.z + xv.z * w2.z + xv.w * w3.z;
                acc[r].w += xv.x * w0.w + xv.y * w1.w + xv.z * w2.w + xv.w * w3.w;
            }
        }
    }
#pragma unroll
    for (int r = 0; r < RPT; ++r) {
        int gr = rbase + r;
        if (gr < nrows) ((float4*)S)[(size_t)gr * CP4 + col4] = acc[r];
    }
}

// ---------------- gather SpMM (layer 1, C=128, fused bias+relu) ----------------
// one wave per node; lane holds 2 columns (float2); coalesced 512B row reads.
__global__ __launch_bounds__(256) void seg_spmm128_k(const int* __restrict__ rp,
                                                     const int* __restrict__ srcs,
                                                     const float* __restrict__ vals,
                                                     const float* __restrict__ S,
                                                     const float* __restrict__ bias,
                                                     float* __restrict__ A, int n) {
    int wid = (blockIdx.x * 256 + threadIdx.x) >> 6;
    int lane = threadIdx.x & 63;
    if (wid >= n) return;
    int beg = rp[wid], end = rp[wid + 1];
    float ax = 0.f, ay = 0.f;
    for (int e = beg; e < end; ++e) {
        int s = srcs[e];
        float v = vals[e];
        float2 m = ((const float2*)S)[(size_t)s * 64 + lane];
        ax += m.x * v;
        ay += m.y * v;
    }
    float2 b = ((const float2*)bias)[lane];
    ax = fmaxf(ax + b.x, 0.f);
    ay = fmaxf(ay + b.y, 0.f);
    float2 r;
    r.x = ax;
    r.y = ay;
    ((float2*)A)[(size_t)wid * 64 + lane] = r;
}

// ---------------- fused layer-2 SpMM (both branches) + gate + projection ------
// one wave per node: x1 = spmm_o(S2o)+b_o2, x2 = spmm_s(S2s)+b_s2 (64 lanes),
// g = (x1.ag1)*x1 + (x2.ag2)*x2 ; a[n]=g.v[0:64], b[n]=g.v[64:128]
__global__ __launch_bounds__(256) void gcn2_gate_k(
    const int* __restrict__ rp_o, const int* __restrict__ src_o,
    const float* __restrict__ val_o, const float* __restrict__ S2o,
    const float* __restrict__ b_o2,
    const int* __restrict__ rp_s, const int* __restrict__ src_s,
    const float* __restrict__ val_s, const float* __restrict__ S2s,
    const float* __restrict__ b_s2,
    const float* __restrict__ ag1, const float* __restrict__ ag2,
    const float* __restrict__ v,
    float* __restrict__ a, float* __restrict__ b, int n) {
    int wid = (blockIdx.x * 256 + threadIdx.x) >> 6;
    int lane = threadIdx.x & 63;
    if (wid >= n) return;

    float x1 = 0.f;
    {
        int beg = rp_o[wid], end = rp_o[wid + 1];
        for (int e = beg; e < end; ++e)
            x1 += S2o[(size_t)src_o[e] * 64 + lane] * val_o[e];
        x1 += b_o2[lane];
    }
    float x2 = 0.f;
    {
        int beg = rp_s[wid], end = rp_s[wid + 1];
        for (int e = beg; e < end; ++e)
            x2 += S2s[(size_t)src_s[e] * 64 + lane] * val_s[e];
        x2 += b_s2[lane];
    }
    float d1 = wave_sum64(x1 * ag1[lane]);
    float d2 = wave_sum64(x2 * ag2[lane]);
    float g = d1 * x1 + d2 * x2;
    float av = wave_sum64(g * v[lane]);
    float bv = wave_sum64(g * v[64 + lane]);
    if (lane == 0) {
        a[wid] = av;
        b[wid] = bv;
    }
}

// v[i] = sum_j dec1_W[i][j] * dec2_W[j];  c = dec1_b . dec2_W + dec2_b
__global__ void vc_k(const float* __restrict__ dec1_W, const float* __restrict__ dec1_b,
                     const float* __restrict__ dec2_W, const float* __restrict__ dec2_b,
                     float* __restrict__ v, float* __restrict__ c) {
    int i = threadIdx.x;  // 128 threads
    float s = 0.f;
    for (int j = 0; j < 64; ++j) s += dec1_W[i * 64 + j] * dec2_W[j];
    v[i] = s;
    if (i == 0) {
        float cc = 0.f;
        for (int j = 0; j < 64; ++j) cc += dec1_b[j] * dec2_W[j];
        *c = cc + dec2_b[0];
    }
}

__global__ __launch_bounds__(256) void decode_k(const int* __restrict__ idx,
                                                const float* __restrict__ a,
                                                const float* __restrict__ b,
                                                const float* __restrict__ c,
                                                float* __restrict__ out, int P) {
    int i = blockIdx.x * 256 + threadIdx.x;
    if (i >= P) return;
    out[i] = a[idx[i]] + b[idx[P + i]] + *c;
}

// ---------------------------------------------------------------------------

extern "C" void kernel_launch(void* const* d_in, const int* in_sizes, int n_in,
                              void* d_out, int out_size, void* d_ws, size_t ws_size,
                              hipStream_t stream) {
    const float* x      = (const float*)d_in[0];
    const int*   o_edges= (const int*)d_in[1];
    const float* o_vals = (const float*)d_in[2];
    const int*   s_edges= (const int*)d_in[3];
    const float* s_vals = (const float*)d_in[4];
    const int*   idx    = (const int*)d_in[5];
    const float* W_o1   = (const float*)d_in[6];
    const float* b_o1   = (const float*)d_in[7];
    const float* W_o2   = (const float*)d_in[8];
    const float* b_o2   = (const float*)d_in[9];
    const float* W_s1   = (const float*)d_in[10];
    const float* b_s1   = (const float*)d_in[11];
    const float* W_s2   = (const float*)d_in[12];
    const float* b_s2   = (const float*)d_in[13];
    const float* ag1    = (const float*)d_in[14];
    const float* ag2    = (const float*)d_in[15];
    const float* dec1_W = (const float*)d_in[16];
    const float* dec1_b = (const float*)d_in[17];
    const float* dec2_W = (const float*)d_in[18];
    const float* dec2_b = (const float*)d_in[19];
    float* out = (float*)d_out;

    const int N = in_sizes[0] / 128;
    const int E = in_sizes[1] / 2;
    const int P = out_size;

    const size_t NB1 = (size_t)N * 128 * 4;  // [N,128] f32 bytes
    const size_t NB2 = (size_t)N * 64 * 4;   // [N,64]  f32 bytes

    char* ws = (char*)d_ws;
    size_t off = 0;
    auto alloc = [&](size_t bytes) {
        char* p = ws + off;
        off += (bytes + 255) & ~(size_t)255;
        return p;
    };

    float* B0 = (float*)alloc(NB1);
    float* B1 = (float*)alloc(NB1);
    float* B2 = (float*)alloc(NB1);
    float* av = (float*)alloc((size_t)P * 4);
    float* bv = (float*)alloc((size_t)P * 4);
    float* vv = (float*)alloc(512);
    float* cc = (float*)alloc(16);
    int* cnt2 = (int*)alloc((size_t)2 * N * 4);  // wo_o | wo_s, ONE block
    int* wo_o = cnt2;
    int* wo_s = cnt2 + N;
    int* rp_o = (int*)alloc((size_t)(N + 1) * 4);
    int* rp_s = (int*)alloc((size_t)(N + 1) * 4);
    int* csr_src_o = (int*)alloc((size_t)E * 4);
    float* csr_val_o = (float*)alloc((size_t)E * 4);
    int* csr_src_s = (int*)alloc((size_t)E * 4);
    float* csr_val_s = (float*)alloc((size_t)E * 4);
    int* bsum = (int*)alloc(512 * 4);

    const int nblk = (N + 255) / 256;
    const int eblk = (E + 255) / 256;

    // ---- CSR build (both graphs) ----
    hipMemsetAsync(cnt2, 0, (size_t)2 * N * 4, stream);  // covers wo_o AND wo_s
    hist_k<<<eblk, 256, 0, stream>>>(o_edges, wo_o, E);
    hist_k<<<eblk, 256, 0, stream>>>(s_edges, wo_s, E);
    scan_a_k<<<nblk, 256, 0, stream>>>(wo_o, rp_o, bsum, N);
    scan_b_k<<<1, 512, 0, stream>>>(bsum, nblk);
    scan_c_k<<<nblk, 256, 0, stream>>>(rp_o, wo_o, bsum, N, E);
    scan_a_k<<<nblk, 256, 0, stream>>>(wo_s, rp_s, bsum, N);
    scan_b_k<<<1, 512, 0, stream>>>(bsum, nblk);
    scan_c_k<<<nblk, 256, 0, stream>>>(rp_s, wo_s, bsum, N, E);
    scatter_k<<<eblk, 256, 0, stream>>>(o_edges, o_vals, wo_o, csr_src_o, csr_val_o, E);
    scatter_k<<<eblk, 256, 0, stream>>>(s_edges, s_vals, wo_s, csr_src_s, csr_val_s, E);

    // ---- decoder collapse ----
    vc_k<<<1, 128, 0, stream>>>(dec1_W, dec1_b, dec2_W, dec2_b, vv, cc);

    // ---- layer 1: S1 = x@W1 ; A1 = relu(spmm(adj,S1)+b1) ----
    const int gblocks = (N + 63) / 64;
    gemm_k<128, 128><<<gblocks, 256, 0, stream>>>(x, W_o1, B0, N);  // S1o
    gemm_k<128, 128><<<gblocks, 256, 0, stream>>>(x, W_s1, B1, N);  // S1s

    const int wblocks = (N * 64 + 255) / 256;  // one wave per node
    seg_spmm128_k<<<wblocks, 256, 0, stream>>>(rp_o, csr_src_o, csr_val_o, B0, b_o1, B2, N);  // A1o
    seg_spmm128_k<<<wblocks, 256, 0, stream>>>(rp_s, csr_src_s, csr_val_s, B1, b_s1, B0, N);  // A1s

    // ---- layer 2 GEMMs: S2o = A1o@W_o2 ; S2s = A1s@W_s2 ----
    float* S2o = B1;                       // S1s dead
    float* S2s = (float*)((char*)B1 + NB2);
    gemm_k<128, 64><<<gblocks, 256, 0, stream>>>(B2, W_o2, S2o, N);
    gemm_k<128, 64><<<gblocks, 256, 0, stream>>>(B0, W_s2, S2s, N);

    // ---- fused layer-2 spmm + gate + projection ----
    gcn2_gate_k<<<wblocks, 256, 0, stream>>>(rp_o, csr_src_o, csr_val_o, S2o, b_o2,
                                             rp_s, csr_src_s, csr_val_s, S2s, b_s2,
                                             ag1, ag2, vv, av, bv, N);

    decode_k<<<(P + 255) / 256, 256, 0, stream>>>(idx, av, bv, cc, out, P);
}

// Round 5
// 983.559 us; speedup vs baseline: 8.7687x; 1.4782x over previous
//
#include <hip/hip_runtime.h>

// ---------------------------------------------------------------------------
// IGCN link prediction, round 4.
// Layer-2 fully collapsed to scalars:
//   a[n] = d1*u1 + d2*u2,  b[n] = d1*w1 + d2*w2,  out[p]=a[i0]+b[i1]+c
// where (d1,u1,w1) = SpMM_o(To)[n] + beta_o,  To[m] = A1o[m] @ (W_o2@{ag1,vlo,vhi})
// To is computed in the layer-1 SpMM epilogue (A1 never materialized).
// Edge loops unrolled x4 for gather-latency hiding.
// ---------------------------------------------------------------------------

__device__ __forceinline__ float wave_sum64(float x) {
#pragma unroll
    for (int o = 32; o > 0; o >>= 1) x += __shfl_xor(x, o, 64);
    return x;
}

// ---------------- CSR construction ----------------

__global__ __launch_bounds__(256) void hist_k(const int* __restrict__ edges,
                                              int* __restrict__ cnt, int E) {
    int e = blockIdx.x * 256 + threadIdx.x;
    if (e >= E) return;
    atomicAdd(&cnt[edges[e]], 1);
}

__global__ __launch_bounds__(256) void scan_a_k(const int* __restrict__ cnt,
                                                int* __restrict__ exc,
                                                int* __restrict__ bsum, int n) {
    __shared__ int sh[256];
    int tid = threadIdx.x;
    int i = blockIdx.x * 256 + tid;
    int v = (i < n) ? cnt[i] : 0;
    sh[tid] = v;
    __syncthreads();
#pragma unroll
    for (int o = 1; o < 256; o <<= 1) {
        int t = (tid >= o) ? sh[tid - o] : 0;
        __syncthreads();
        sh[tid] += t;
        __syncthreads();
    }
    if (i < n) exc[i] = sh[tid] - v;
    if (tid == 255) bsum[blockIdx.x] = sh[tid];
}

__global__ __launch_bounds__(512) void scan_b_k(int* __restrict__ bsum, int nblk) {
    __shared__ int sh[512];
    int t = threadIdx.x;
    int v = (t < nblk) ? bsum[t] : 0;
    sh[t] = v;
    __syncthreads();
#pragma unroll
    for (int o = 1; o < 512; o <<= 1) {
        int tv = (t >= o) ? sh[t - o] : 0;
        __syncthreads();
        sh[t] += tv;
        __syncthreads();
    }
    if (t < nblk) bsum[t] = sh[t] - v;
}

__global__ __launch_bounds__(256) void scan_c_k(int* __restrict__ rp,
                                                int* __restrict__ wo,
                                                const int* __restrict__ bsum,
                                                int n, int E) {
    int i = blockIdx.x * 256 + threadIdx.x;
    if (i < n) {
        int v = rp[i] + bsum[blockIdx.x];
        rp[i] = v;
        wo[i] = v;
    }
    if (i == 0) rp[n] = E;
}

__global__ __launch_bounds__(256) void scatter_k(const int* __restrict__ edges,
                                                 const float* __restrict__ vals,
                                                 int* __restrict__ wo,
                                                 int* __restrict__ csr_src,
                                                 float* __restrict__ csr_val, int E) {
    int e = blockIdx.x * 256 + threadIdx.x;
    if (e >= E) return;
    int dst = edges[e];
    int pos = atomicAdd(&wo[dst], 1);
    csr_src[pos] = edges[E + e];
    csr_val[pos] = vals[e];
}

// ---------------- precompute projections ----------------
// vv[i] = dec1_W[i]·dec2_W ; c = dec1_b·dec2_W + dec2_b
// Mo[r*128+j] = W_o2[j,:]·{ag1,vlo,vhi}[r] ; Ms same with W_s2,ag2
// beta[0..2] = b_o2·{ag1,vlo,vhi} ; beta[4..6] = b_s2·{ag2,vlo,vhi}
__global__ void prep_k(const float* __restrict__ dec1_W, const float* __restrict__ dec1_b,
                       const float* __restrict__ dec2_W, const float* __restrict__ dec2_b,
                       const float* __restrict__ W_o2, const float* __restrict__ b_o2,
                       const float* __restrict__ W_s2, const float* __restrict__ b_s2,
                       const float* __restrict__ ag1, const float* __restrict__ ag2,
                       float* __restrict__ Mo, float* __restrict__ Ms,
                       float* __restrict__ beta, float* __restrict__ cc) {
    __shared__ float vsh[128];
    int t = threadIdx.x;  // 128 threads
    float s = 0.f;
    for (int j = 0; j < 64; ++j) s += dec1_W[t * 64 + j] * dec2_W[j];
    vsh[t] = s;
    __syncthreads();
    const float* vlo = vsh;
    const float* vhi = vsh + 64;
    float m0 = 0, m1 = 0, m2 = 0, n0 = 0, n1 = 0, n2 = 0;
    for (int k = 0; k < 64; ++k) {
        float wo = W_o2[t * 64 + k], wsv = W_s2[t * 64 + k];
        m0 += wo * ag1[k];  m1 += wo * vlo[k];  m2 += wo * vhi[k];
        n0 += wsv * ag2[k]; n1 += wsv * vlo[k]; n2 += wsv * vhi[k];
    }
    Mo[0 * 128 + t] = m0; Mo[1 * 128 + t] = m1; Mo[2 * 128 + t] = m2;
    Ms[0 * 128 + t] = n0; Ms[1 * 128 + t] = n1; Ms[2 * 128 + t] = n2;
    if (t == 0) {
        float b0 = 0, b1 = 0, b2 = 0, s0 = 0, s1 = 0, s2 = 0, c0 = 0;
        for (int k = 0; k < 64; ++k) {
            b0 += b_o2[k] * ag1[k]; b1 += b_o2[k] * vlo[k]; b2 += b_o2[k] * vhi[k];
            s0 += b_s2[k] * ag2[k]; s1 += b_s2[k] * vlo[k]; s2 += b_s2[k] * vhi[k];
            c0 += dec1_b[k] * dec2_W[k];
        }
        beta[0] = b0; beta[1] = b1; beta[2] = b2;
        beta[4] = s0; beta[5] = s1; beta[6] = s2;
        *cc = c0 + dec2_b[0];
    }
}

// ---------------- dense GEMM: S[nrows,C] = X[nrows,K] @ W[K,C] ----------------

template <int K, int C>
__global__ __launch_bounds__(256) void gemm_k(const float* __restrict__ X,
                                              const float* __restrict__ W,
                                              float* __restrict__ S, int nrows) {
    constexpr int ROWS = 64;
    constexpr int CP4 = C / 4;
    constexpr int RG = 256 / CP4;
    constexpr int RPT = ROWS / RG;
    __shared__ float WL[K * C];

    const int t = threadIdx.x;
    for (int i = t; i < K * C / 4; i += 256)
        ((float4*)WL)[i] = ((const float4*)W)[i];
    __syncthreads();

    const int row0 = blockIdx.x * ROWS;
    const int col4 = t % CP4;
    const int rg = t / CP4;
    const int rbase = row0 + rg * RPT;

    float4 acc[RPT];
#pragma unroll
    for (int r = 0; r < RPT; ++r) acc[r] = make_float4(0.f, 0.f, 0.f, 0.f);

#pragma unroll 4
    for (int k4 = 0; k4 < K / 4; ++k4) {
        float4 w0 = ((const float4*)WL)[(4 * k4 + 0) * CP4 + col4];
        float4 w1 = ((const float4*)WL)[(4 * k4 + 1) * CP4 + col4];
        float4 w2 = ((const float4*)WL)[(4 * k4 + 2) * CP4 + col4];
        float4 w3 = ((const float4*)WL)[(4 * k4 + 3) * CP4 + col4];
#pragma unroll
        for (int r = 0; r < RPT; ++r) {
            int gr = rbase + r;
            if (gr < nrows) {
                float4 xv = ((const float4*)X)[(size_t)gr * (K / 4) + k4];
                acc[r].x += xv.x * w0.x + xv.y * w1.x + xv.z * w2.x + xv.w * w3.x;
                acc[r].y += xv.x * w0.y + xv.y * w1.y + xv.z * w2.y + xv.w * w3.y;
                acc[r].z += xv.x * w0.z + xv.y * w1.z + xv.z * w2.z + xv.w * w3.z;
                acc[r].w += xv.x * w0.w + xv.y * w1.w + xv.z * w2.w + xv.w * w3.w;
            }
        }
    }
#pragma unroll
    for (int r = 0; r < RPT; ++r) {
        int gr = rbase + r;
        if (gr < nrows) ((float4*)S)[(size_t)gr * CP4 + col4] = acc[r];
    }
}

// ------- layer-1 gather SpMM + bias + relu + 3-way projection (fused) -------
// one wave per node; lane holds 2 of 128 cols; edge loop unrolled x4.
// T[n] = ( relu_row·Mo_col0, ·Mo_col1, ·Mo_col2 )  [beta added later]
__global__ __launch_bounds__(256) void seg_spmm_fused_k(
    const int* __restrict__ rp, const int* __restrict__ srcs,
    const float* __restrict__ vals, const float* __restrict__ S,
    const float* __restrict__ bias, const float* __restrict__ M,
    float4* __restrict__ T, int n) {
    int wid = (blockIdx.x * 256 + threadIdx.x) >> 6;
    int lane = threadIdx.x & 63;
    if (wid >= n) return;
    int e = rp[wid], end = rp[wid + 1];
    float ax = 0.f, ay = 0.f;
    for (; e + 3 < end; e += 4) {
        int s0 = srcs[e], s1 = srcs[e + 1], s2 = srcs[e + 2], s3 = srcs[e + 3];
        float v0 = vals[e], v1 = vals[e + 1], v2 = vals[e + 2], v3 = vals[e + 3];
        float2 m0 = ((const float2*)S)[s0 * 64 + lane];
        float2 m1 = ((const float2*)S)[s1 * 64 + lane];
        float2 m2 = ((const float2*)S)[s2 * 64 + lane];
        float2 m3 = ((const float2*)S)[s3 * 64 + lane];
        ax += m0.x * v0 + m1.x * v1 + m2.x * v2 + m3.x * v3;
        ay += m0.y * v0 + m1.y * v1 + m2.y * v2 + m3.y * v3;
    }
    for (; e < end; ++e) {
        int s = srcs[e];
        float v = vals[e];
        float2 m = ((const float2*)S)[s * 64 + lane];
        ax += m.x * v;
        ay += m.y * v;
    }
    float2 bb = ((const float2*)bias)[lane];
    ax = fmaxf(ax + bb.x, 0.f);
    ay = fmaxf(ay + bb.y, 0.f);
    float2 M0 = ((const float2*)(M + 0 * 128))[lane];
    float2 M1 = ((const float2*)(M + 1 * 128))[lane];
    float2 M2 = ((const float2*)(M + 2 * 128))[lane];
    float d = wave_sum64(ax * M0.x + ay * M0.y);
    float u = wave_sum64(ax * M1.x + ay * M1.y);
    float w = wave_sum64(ax * M2.x + ay * M2.y);
    if (lane == 0) T[wid] = make_float4(d, u, w, 0.f);
}

// ------- layer-2 scalar SpMM (both graphs) + gate + decode projections -------
// one THREAD per node; To/Ts are [N] float4 (1.6 MB, L2-resident).
__global__ __launch_bounds__(256) void gate_k(
    const int* __restrict__ rp_o, const int* __restrict__ src_o,
    const float* __restrict__ val_o, const float4* __restrict__ To,
    const int* __restrict__ rp_s, const int* __restrict__ src_s,
    const float* __restrict__ val_s, const float4* __restrict__ Ts,
    const float* __restrict__ beta,
    float* __restrict__ a, float* __restrict__ b, int n) {
    int i = blockIdx.x * 256 + threadIdx.x;
    if (i >= n) return;
    float d1 = 0.f, u1 = 0.f, w1 = 0.f;
    {
        int e = rp_o[i], end = rp_o[i + 1];
        for (; e + 3 < end; e += 4) {
            float4 t0 = To[src_o[e]];
            float4 t1 = To[src_o[e + 1]];
            float4 t2 = To[src_o[e + 2]];
            float4 t3 = To[src_o[e + 3]];
            float v0 = val_o[e], v1 = val_o[e + 1], v2 = val_o[e + 2], v3 = val_o[e + 3];
            d1 += t0.x * v0 + t1.x * v1 + t2.x * v2 + t3.x * v3;
            u1 += t0.y * v0 + t1.y * v1 + t2.y * v2 + t3.y * v3;
            w1 += t0.z * v0 + t1.z * v1 + t2.z * v2 + t3.z * v3;
        }
        for (; e < end; ++e) {
            float4 t = To[src_o[e]];
            float v = val_o[e];
            d1 += t.x * v; u1 += t.y * v; w1 += t.z * v;
        }
    }
    float d2 = 0.f, u2 = 0.f, w2 = 0.f;
    {
        int e = rp_s[i], end = rp_s[i + 1];
        for (; e + 3 < end; e += 4) {
            float4 t0 = Ts[src_s[e]];
            float4 t1 = Ts[src_s[e + 1]];
            float4 t2 = Ts[src_s[e + 2]];
            float4 t3 = Ts[src_s[e + 3]];
            float v0 = val_s[e], v1 = val_s[e + 1], v2 = val_s[e + 2], v3 = val_s[e + 3];
            d2 += t0.x * v0 + t1.x * v1 + t2.x * v2 + t3.x * v3;
            u2 += t0.y * v0 + t1.y * v1 + t2.y * v2 + t3.y * v3;
            w2 += t0.z * v0 + t1.z * v1 + t2.z * v2 + t3.z * v3;
        }
        for (; e < end; ++e) {
            float4 t = Ts[src_s[e]];
            float v = val_s[e];
            d2 += t.x * v; u2 += t.y * v; w2 += t.z * v;
        }
    }
    d1 += beta[0]; u1 += beta[1]; w1 += beta[2];
    d2 += beta[4]; u2 += beta[5]; w2 += beta[6];
    a[i] = d1 * u1 + d2 * u2;
    b[i] = d1 * w1 + d2 * w2;
}

__global__ __launch_bounds__(256) void decode_k(const int* __restrict__ idx,
                                                const float* __restrict__ a,
                                                const float* __restrict__ b,
                                                const float* __restrict__ c,
                                                float* __restrict__ out, int P) {
    int i = blockIdx.x * 256 + threadIdx.x;
    if (i >= P) return;
    out[i] = a[idx[i]] + b[idx[P + i]] + *c;
}

// ---------------------------------------------------------------------------

extern "C" void kernel_launch(void* const* d_in, const int* in_sizes, int n_in,
                              void* d_out, int out_size, void* d_ws, size_t ws_size,
                              hipStream_t stream) {
    const float* x      = (const float*)d_in[0];
    const int*   o_edges= (const int*)d_in[1];
    const float* o_vals = (const float*)d_in[2];
    const int*   s_edges= (const int*)d_in[3];
    const float* s_vals = (const float*)d_in[4];
    const int*   idx    = (const int*)d_in[5];
    const float* W_o1   = (const float*)d_in[6];
    const float* b_o1   = (const float*)d_in[7];
    const float* W_o2   = (const float*)d_in[8];
    const float* b_o2   = (const float*)d_in[9];
    const float* W_s1   = (const float*)d_in[10];
    const float* b_s1   = (const float*)d_in[11];
    const float* W_s2   = (const float*)d_in[12];
    const float* b_s2   = (const float*)d_in[13];
    const float* ag1    = (const float*)d_in[14];
    const float* ag2    = (const float*)d_in[15];
    const float* dec1_W = (const float*)d_in[16];
    const float* dec1_b = (const float*)d_in[17];
    const float* dec2_W = (const float*)d_in[18];
    const float* dec2_b = (const float*)d_in[19];
    float* out = (float*)d_out;

    const int N = in_sizes[0] / 128;
    const int E = in_sizes[1] / 2;
    const int P = out_size;

    const size_t NB1 = (size_t)N * 128 * 4;  // [N,128] f32 bytes

    char* ws = (char*)d_ws;
    size_t off = 0;
    auto alloc = [&](size_t bytes) {
        char* p = ws + off;
        off += (bytes + 255) & ~(size_t)255;
        return p;
    };

    float* B0 = (float*)alloc(NB1);            // S1o
    float* B1 = (float*)alloc(NB1);            // S1s
    float4* To = (float4*)alloc((size_t)N * 16);
    float4* Ts = (float4*)alloc((size_t)N * 16);
    float* av = (float*)alloc((size_t)P * 4);
    float* bv = (float*)alloc((size_t)P * 4);
    float* Mo = (float*)alloc(3 * 128 * 4);
    float* Ms = (float*)alloc(3 * 128 * 4);
    float* beta = (float*)alloc(32);
    float* cc = (float*)alloc(16);
    int* cnt2 = (int*)alloc((size_t)2 * N * 4);  // wo_o | wo_s, one block
    int* wo_o = cnt2;
    int* wo_s = cnt2 + N;
    int* rp_o = (int*)alloc((size_t)(N + 1) * 4);
    int* rp_s = (int*)alloc((size_t)(N + 1) * 4);
    int* csr_src_o = (int*)alloc((size_t)E * 4);
    float* csr_val_o = (float*)alloc((size_t)E * 4);
    int* csr_src_s = (int*)alloc((size_t)E * 4);
    float* csr_val_s = (float*)alloc((size_t)E * 4);
    int* bsum = (int*)alloc(512 * 4);

    const int nblk = (N + 255) / 256;
    const int eblk = (E + 255) / 256;

    // ---- CSR build (both graphs) ----
    hipMemsetAsync(cnt2, 0, (size_t)2 * N * 4, stream);
    hist_k<<<eblk, 256, 0, stream>>>(o_edges, wo_o, E);
    hist_k<<<eblk, 256, 0, stream>>>(s_edges, wo_s, E);
    scan_a_k<<<nblk, 256, 0, stream>>>(wo_o, rp_o, bsum, N);
    scan_b_k<<<1, 512, 0, stream>>>(bsum, nblk);
    scan_c_k<<<nblk, 256, 0, stream>>>(rp_o, wo_o, bsum, N, E);
    scan_a_k<<<nblk, 256, 0, stream>>>(wo_s, rp_s, bsum, N);
    scan_b_k<<<1, 512, 0, stream>>>(bsum, nblk);
    scan_c_k<<<nblk, 256, 0, stream>>>(rp_s, wo_s, bsum, N, E);
    scatter_k<<<eblk, 256, 0, stream>>>(o_edges, o_vals, wo_o, csr_src_o, csr_val_o, E);
    scatter_k<<<eblk, 256, 0, stream>>>(s_edges, s_vals, wo_s, csr_src_s, csr_val_s, E);

    // ---- projection precompute ----
    prep_k<<<1, 128, 0, stream>>>(dec1_W, dec1_b, dec2_W, dec2_b,
                                  W_o2, b_o2, W_s2, b_s2, ag1, ag2,
                                  Mo, Ms, beta, cc);

    // ---- layer 1 GEMMs ----
    const int gblocks = (N + 63) / 64;
    gemm_k<128, 128><<<gblocks, 256, 0, stream>>>(x, W_o1, B0, N);  // S1o
    gemm_k<128, 128><<<gblocks, 256, 0, stream>>>(x, W_s1, B1, N);  // S1s

    // ---- layer-1 SpMM + bias + relu + projection to 3 scalars ----
    const int wblocks = (N * 64 + 255) / 256;
    seg_spmm_fused_k<<<wblocks, 256, 0, stream>>>(rp_o, csr_src_o, csr_val_o, B0,
                                                  b_o1, Mo, To, N);
    seg_spmm_fused_k<<<wblocks, 256, 0, stream>>>(rp_s, csr_src_s, csr_val_s, B1,
                                                  b_s1, Ms, Ts, N);

    // ---- layer-2 scalar SpMM + gate ----
    gate_k<<<nblk, 256, 0, stream>>>(rp_o, csr_src_o, csr_val_o, To,
                                     rp_s, csr_src_s, csr_val_s, Ts,
                                     beta, av, bv, N);

    decode_k<<<(P + 255) / 256, 256, 0, stream>>>(idx, av, bv, cc, out, P);
}

// Round 6
// 744.750 us; speedup vs baseline: 11.5805x; 1.3207x over previous
//
#include <hip/hip_runtime.h>

// ---------------------------------------------------------------------------
// IGCN link prediction, round 5.
// - Layer-2 collapsed to scalars (R4).
// - NEW: register-blocked tiled f32 GEMM (128x128 C-tile, 16-wide K panels in
//   LDS, 8x8 per-thread register tile), both branches in one launch (grid.y=2).
// - NEW: both layer-1 SpMM branches in one launch (grid.y=2).
// ---------------------------------------------------------------------------

__device__ __forceinline__ float wave_sum64(float x) {
#pragma unroll
    for (int o = 32; o > 0; o >>= 1) x += __shfl_xor(x, o, 64);
    return x;
}

// ---------------- CSR construction ----------------

__global__ __launch_bounds__(256) void hist_k(const int* __restrict__ edges,
                                              int* __restrict__ cnt, int E) {
    int e = blockIdx.x * 256 + threadIdx.x;
    if (e >= E) return;
    atomicAdd(&cnt[edges[e]], 1);
}

__global__ __launch_bounds__(256) void scan_a_k(const int* __restrict__ cnt,
                                                int* __restrict__ exc,
                                                int* __restrict__ bsum, int n) {
    __shared__ int sh[256];
    int tid = threadIdx.x;
    int i = blockIdx.x * 256 + tid;
    int v = (i < n) ? cnt[i] : 0;
    sh[tid] = v;
    __syncthreads();
#pragma unroll
    for (int o = 1; o < 256; o <<= 1) {
        int t = (tid >= o) ? sh[tid - o] : 0;
        __syncthreads();
        sh[tid] += t;
        __syncthreads();
    }
    if (i < n) exc[i] = sh[tid] - v;
    if (tid == 255) bsum[blockIdx.x] = sh[tid];
}

__global__ __launch_bounds__(512) void scan_b_k(int* __restrict__ bsum, int nblk) {
    __shared__ int sh[512];
    int t = threadIdx.x;
    int v = (t < nblk) ? bsum[t] : 0;
    sh[t] = v;
    __syncthreads();
#pragma unroll
    for (int o = 1; o < 512; o <<= 1) {
        int tv = (t >= o) ? sh[t - o] : 0;
        __syncthreads();
        sh[t] += tv;
        __syncthreads();
    }
    if (t < nblk) bsum[t] = sh[t] - v;
}

__global__ __launch_bounds__(256) void scan_c_k(int* __restrict__ rp,
                                                int* __restrict__ wo,
                                                const int* __restrict__ bsum,
                                                int n, int E) {
    int i = blockIdx.x * 256 + threadIdx.x;
    if (i < n) {
        int v = rp[i] + bsum[blockIdx.x];
        rp[i] = v;
        wo[i] = v;
    }
    if (i == 0) rp[n] = E;
}

__global__ __launch_bounds__(256) void scatter_k(const int* __restrict__ edges,
                                                 const float* __restrict__ vals,
                                                 int* __restrict__ wo,
                                                 int* __restrict__ csr_src,
                                                 float* __restrict__ csr_val, int E) {
    int e = blockIdx.x * 256 + threadIdx.x;
    if (e >= E) return;
    int dst = edges[e];
    int pos = atomicAdd(&wo[dst], 1);
    csr_src[pos] = edges[E + e];
    csr_val[pos] = vals[e];
}

// ---------------- precompute projections ----------------
__global__ void prep_k(const float* __restrict__ dec1_W, const float* __restrict__ dec1_b,
                       const float* __restrict__ dec2_W, const float* __restrict__ dec2_b,
                       const float* __restrict__ W_o2, const float* __restrict__ b_o2,
                       const float* __restrict__ W_s2, const float* __restrict__ b_s2,
                       const float* __restrict__ ag1, const float* __restrict__ ag2,
                       float* __restrict__ Mo, float* __restrict__ Ms,
                       float* __restrict__ beta, float* __restrict__ cc) {
    __shared__ float vsh[128];
    int t = threadIdx.x;  // 128 threads
    float s = 0.f;
    for (int j = 0; j < 64; ++j) s += dec1_W[t * 64 + j] * dec2_W[j];
    vsh[t] = s;
    __syncthreads();
    const float* vlo = vsh;
    const float* vhi = vsh + 64;
    float m0 = 0, m1 = 0, m2 = 0, n0 = 0, n1 = 0, n2 = 0;
    for (int k = 0; k < 64; ++k) {
        float wo = W_o2[t * 64 + k], wsv = W_s2[t * 64 + k];
        m0 += wo * ag1[k];  m1 += wo * vlo[k];  m2 += wo * vhi[k];
        n0 += wsv * ag2[k]; n1 += wsv * vlo[k]; n2 += wsv * vhi[k];
    }
    Mo[0 * 128 + t] = m0; Mo[1 * 128 + t] = m1; Mo[2 * 128 + t] = m2;
    Ms[0 * 128 + t] = n0; Ms[1 * 128 + t] = n1; Ms[2 * 128 + t] = n2;
    if (t == 0) {
        float b0 = 0, b1 = 0, b2 = 0, s0 = 0, s1 = 0, s2 = 0, c0 = 0;
        for (int k = 0; k < 64; ++k) {
            b0 += b_o2[k] * ag1[k]; b1 += b_o2[k] * vlo[k]; b2 += b_o2[k] * vhi[k];
            s0 += b_s2[k] * ag2[k]; s1 += b_s2[k] * vlo[k]; s2 += b_s2[k] * vhi[k];
            c0 += dec1_b[k] * dec2_W[k];
        }
        beta[0] = b0; beta[1] = b1; beta[2] = b2;
        beta[4] = s0; beta[5] = s1; beta[6] = s2;
        *cc = c0 + dec2_b[0];
    }
}

// ---------------- tiled f32 GEMM, both branches in one launch ----------------
// S[b][n,128] = X[n,128] @ W[b][128,128].  C-tile 128x128 per block,
// K panels of 16 staged in LDS for X and W; 8x8 register tile per thread.
// X_lds stride 17 (conflict-free b32 reads), W_lds stride 132 (b128 reads).
__global__ __launch_bounds__(256) void gemm2_k(const float* __restrict__ X,
                                               const float* __restrict__ W0,
                                               const float* __restrict__ W1,
                                               float* __restrict__ S0,
                                               float* __restrict__ S1, int nrows) {
    __shared__ __align__(16) float XL[128 * 17];
    __shared__ __align__(16) float WL[16 * 132];

    const float* W = (blockIdx.y == 0) ? W0 : W1;
    float* S = (blockIdx.y == 0) ? S0 : S1;

    const int tid = threadIdx.x;
    const int tx = tid & 15;          // col group: cols c0 = tx*8
    const int ty = tid >> 4;          // row group: rows r0 = ty*8
    const int row0 = blockIdx.x * 128;
    const int c0 = tx * 8;
    const int r0 = ty * 8;

    float acc[8][8];
#pragma unroll
    for (int i = 0; i < 8; ++i)
#pragma unroll
        for (int j = 0; j < 8; ++j) acc[i][j] = 0.f;

    const float4* X4 = (const float4*)X;  // row stride 32 float4s
    const float4* W4 = (const float4*)W;

    for (int kp = 0; kp < 8; ++kp) {
        if (kp) __syncthreads();
        // stage X tile [128 rows][16 k]: 512 float4s, 2 per thread
#pragma unroll
        for (int it = 0; it < 2; ++it) {
            int f = it * 256 + tid;
            int r = f >> 2, kq = f & 3;
            int gr = row0 + r;
            if (gr >= nrows) gr = nrows - 1;  // clamp (stores are guarded)
            float4 v = X4[(size_t)gr * 32 + kp * 4 + kq];
            int base = r * 17 + kq * 4;
            XL[base + 0] = v.x; XL[base + 1] = v.y;
            XL[base + 2] = v.z; XL[base + 3] = v.w;
        }
        // stage W tile [16 k][128 c]: 512 float4s, 2 per thread
#pragma unroll
        for (int it = 0; it < 2; ++it) {
            int f = it * 256 + tid;
            int kk = f >> 5, cq = f & 31;
            float4 v = W4[(size_t)(kp * 16 + kk) * 32 + cq];
            *(float4*)&WL[kk * 132 + cq * 4] = v;
        }
        __syncthreads();

#pragma unroll 4
        for (int kk = 0; kk < 16; ++kk) {
            float xr[8];
#pragma unroll
            for (int i = 0; i < 8; ++i) xr[i] = XL[(r0 + i) * 17 + kk];
            float4 wa = *(const float4*)&WL[kk * 132 + c0];
            float4 wb = *(const float4*)&WL[kk * 132 + c0 + 4];
            float wv[8] = {wa.x, wa.y, wa.z, wa.w, wb.x, wb.y, wb.z, wb.w};
#pragma unroll
            for (int i = 0; i < 8; ++i)
#pragma unroll
                for (int j = 0; j < 8; ++j) acc[i][j] += xr[i] * wv[j];
        }
    }

#pragma unroll
    for (int i = 0; i < 8; ++i) {
        int gr = row0 + r0 + i;
        if (gr < nrows) {
            float4 v0 = make_float4(acc[i][0], acc[i][1], acc[i][2], acc[i][3]);
            float4 v1 = make_float4(acc[i][4], acc[i][5], acc[i][6], acc[i][7]);
            ((float4*)S)[(size_t)gr * 32 + tx * 2 + 0] = v0;
            ((float4*)S)[(size_t)gr * 32 + tx * 2 + 1] = v1;
        }
    }
}

// ------- layer-1 gather SpMM + bias + relu + 3-way projection (fused) -------
// both branches in one launch (blockIdx.y). one wave per node; lane = 2 cols.
__global__ __launch_bounds__(256) void seg_spmm_fused2_k(
    const int* __restrict__ rp_o, const int* __restrict__ src_o,
    const float* __restrict__ val_o, const float* __restrict__ So,
    const float* __restrict__ bias_o, const float* __restrict__ Mo,
    float4* __restrict__ To,
    const int* __restrict__ rp_s, const int* __restrict__ src_s,
    const float* __restrict__ val_s, const float* __restrict__ Ss,
    const float* __restrict__ bias_s, const float* __restrict__ Ms,
    float4* __restrict__ Ts, int n) {
    const int* rp;  const int* srcs;  const float* vals;
    const float* S; const float* bias; const float* M; float4* T;
    if (blockIdx.y == 0) {
        rp = rp_o; srcs = src_o; vals = val_o; S = So; bias = bias_o; M = Mo; T = To;
    } else {
        rp = rp_s; srcs = src_s; vals = val_s; S = Ss; bias = bias_s; M = Ms; T = Ts;
    }
    int wid = (blockIdx.x * 256 + threadIdx.x) >> 6;
    int lane = threadIdx.x & 63;
    if (wid >= n) return;
    int e = rp[wid], end = rp[wid + 1];
    float ax = 0.f, ay = 0.f;
    for (; e + 3 < end; e += 4) {
        int s0 = srcs[e], s1 = srcs[e + 1], s2 = srcs[e + 2], s3 = srcs[e + 3];
        float v0 = vals[e], v1 = vals[e + 1], v2 = vals[e + 2], v3 = vals[e + 3];
        float2 m0 = ((const float2*)S)[s0 * 64 + lane];
        float2 m1 = ((const float2*)S)[s1 * 64 + lane];
        float2 m2 = ((const float2*)S)[s2 * 64 + lane];
        float2 m3 = ((const float2*)S)[s3 * 64 + lane];
        ax += m0.x * v0 + m1.x * v1 + m2.x * v2 + m3.x * v3;
        ay += m0.y * v0 + m1.y * v1 + m2.y * v2 + m3.y * v3;
    }
    for (; e < end; ++e) {
        int s = srcs[e];
        float v = vals[e];
        float2 m = ((const float2*)S)[s * 64 + lane];
        ax += m.x * v;
        ay += m.y * v;
    }
    float2 bb = ((const float2*)bias)[lane];
    ax = fmaxf(ax + bb.x, 0.f);
    ay = fmaxf(ay + bb.y, 0.f);
    float2 M0 = ((const float2*)(M + 0 * 128))[lane];
    float2 M1 = ((const float2*)(M + 1 * 128))[lane];
    float2 M2 = ((const float2*)(M + 2 * 128))[lane];
    float d = wave_sum64(ax * M0.x + ay * M0.y);
    float u = wave_sum64(ax * M1.x + ay * M1.y);
    float w = wave_sum64(ax * M2.x + ay * M2.y);
    if (lane == 0) T[wid] = make_float4(d, u, w, 0.f);
}

// ------- layer-2 scalar SpMM (both graphs) + gate + decode projections -------
__global__ __launch_bounds__(256) void gate_k(
    const int* __restrict__ rp_o, const int* __restrict__ src_o,
    const float* __restrict__ val_o, const float4* __restrict__ To,
    const int* __restrict__ rp_s, const int* __restrict__ src_s,
    const float* __restrict__ val_s, const float4* __restrict__ Ts,
    const float* __restrict__ beta,
    float* __restrict__ a, float* __restrict__ b, int n) {
    int i = blockIdx.x * 256 + threadIdx.x;
    if (i >= n) return;
    float d1 = 0.f, u1 = 0.f, w1 = 0.f;
    {
        int e = rp_o[i], end = rp_o[i + 1];
        for (; e + 3 < end; e += 4) {
            float4 t0 = To[src_o[e]];
            float4 t1 = To[src_o[e + 1]];
            float4 t2 = To[src_o[e + 2]];
            float4 t3 = To[src_o[e + 3]];
            float v0 = val_o[e], v1 = val_o[e + 1], v2 = val_o[e + 2], v3 = val_o[e + 3];
            d1 += t0.x * v0 + t1.x * v1 + t2.x * v2 + t3.x * v3;
            u1 += t0.y * v0 + t1.y * v1 + t2.y * v2 + t3.y * v3;
            w1 += t0.z * v0 + t1.z * v1 + t2.z * v2 + t3.z * v3;
        }
        for (; e < end; ++e) {
            float4 t = To[src_o[e]];
            float v = val_o[e];
            d1 += t.x * v; u1 += t.y * v; w1 += t.z * v;
        }
    }
    float d2 = 0.f, u2 = 0.f, w2 = 0.f;
    {
        int e = rp_s[i], end = rp_s[i + 1];
        for (; e + 3 < end; e += 4) {
            float4 t0 = Ts[src_s[e]];
            float4 t1 = Ts[src_s[e + 1]];
            float4 t2 = Ts[src_s[e + 2]];
            float4 t3 = Ts[src_s[e + 3]];
            float v0 = val_s[e], v1 = val_s[e + 1], v2 = val_s[e + 2], v3 = val_s[e + 3];
            d2 += t0.x * v0 + t1.x * v1 + t2.x * v2 + t3.x * v3;
            u2 += t0.y * v0 + t1.y * v1 + t2.y * v2 + t3.y * v3;
            w2 += t0.z * v0 + t1.z * v1 + t2.z * v2 + t3.z * v3;
        }
        for (; e < end; ++e) {
            float4 t = Ts[src_s[e]];
            float v = val_s[e];
            d2 += t.x * v; u2 += t.y * v; w2 += t.z * v;
        }
    }
    d1 += beta[0]; u1 += beta[1]; w1 += beta[2];
    d2 += beta[4]; u2 += beta[5]; w2 += beta[6];
    a[i] = d1 * u1 + d2 * u2;
    b[i] = d1 * w1 + d2 * w2;
}

__global__ __launch_bounds__(256) void decode_k(const int* __restrict__ idx,
                                                const float* __restrict__ a,
                                                const float* __restrict__ b,
                                                const float* __restrict__ c,
                                                float* __restrict__ out, int P) {
    int i = blockIdx.x * 256 + threadIdx.x;
    if (i >= P) return;
    out[i] = a[idx[i]] + b[idx[P + i]] + *c;
}

// ---------------------------------------------------------------------------

extern "C" void kernel_launch(void* const* d_in, const int* in_sizes, int n_in,
                              void* d_out, int out_size, void* d_ws, size_t ws_size,
                              hipStream_t stream) {
    const float* x      = (const float*)d_in[0];
    const int*   o_edges= (const int*)d_in[1];
    const float* o_vals = (const float*)d_in[2];
    const int*   s_edges= (const int*)d_in[3];
    const float* s_vals = (const float*)d_in[4];
    const int*   idx    = (const int*)d_in[5];
    const float* W_o1   = (const float*)d_in[6];
    const float* b_o1   = (const float*)d_in[7];
    const float* W_o2   = (const float*)d_in[8];
    const float* b_o2   = (const float*)d_in[9];
    const float* W_s1   = (const float*)d_in[10];
    const float* b_s1   = (const float*)d_in[11];
    const float* W_s2   = (const float*)d_in[12];
    const float* b_s2   = (const float*)d_in[13];
    const float* ag1    = (const float*)d_in[14];
    const float* ag2    = (const float*)d_in[15];
    const float* dec1_W = (const float*)d_in[16];
    const float* dec1_b = (const float*)d_in[17];
    const float* dec2_W = (const float*)d_in[18];
    const float* dec2_b = (const float*)d_in[19];
    float* out = (float*)d_out;

    const int N = in_sizes[0] / 128;
    const int E = in_sizes[1] / 2;
    const int P = out_size;

    const size_t NB1 = (size_t)N * 128 * 4;  // [N,128] f32 bytes

    char* ws = (char*)d_ws;
    size_t off = 0;
    auto alloc = [&](size_t bytes) {
        char* p = ws + off;
        off += (bytes + 255) & ~(size_t)255;
        return p;
    };

    float* B0 = (float*)alloc(NB1);            // S1o
    float* B1 = (float*)alloc(NB1);            // S1s
    float4* To = (float4*)alloc((size_t)N * 16);
    float4* Ts = (float4*)alloc((size_t)N * 16);
    float* av = (float*)alloc((size_t)P * 4);
    float* bv = (float*)alloc((size_t)P * 4);
    float* Mo = (float*)alloc(3 * 128 * 4);
    float* Ms = (float*)alloc(3 * 128 * 4);
    float* beta = (float*)alloc(32);
    float* cc = (float*)alloc(16);
    int* cnt2 = (int*)alloc((size_t)2 * N * 4);  // wo_o | wo_s, one block
    int* wo_o = cnt2;
    int* wo_s = cnt2 + N;
    int* rp_o = (int*)alloc((size_t)(N + 1) * 4);
    int* rp_s = (int*)alloc((size_t)(N + 1) * 4);
    int* csr_src_o = (int*)alloc((size_t)E * 4);
    float* csr_val_o = (float*)alloc((size_t)E * 4);
    int* csr_src_s = (int*)alloc((size_t)E * 4);
    float* csr_val_s = (float*)alloc((size_t)E * 4);
    int* bsum = (int*)alloc(512 * 4);

    const int nblk = (N + 255) / 256;
    const int eblk = (E + 255) / 256;

    // ---- CSR build (both graphs) ----
    hipMemsetAsync(cnt2, 0, (size_t)2 * N * 4, stream);
    hist_k<<<eblk, 256, 0, stream>>>(o_edges, wo_o, E);
    hist_k<<<eblk, 256, 0, stream>>>(s_edges, wo_s, E);
    scan_a_k<<<nblk, 256, 0, stream>>>(wo_o, rp_o, bsum, N);
    scan_b_k<<<1, 512, 0, stream>>>(bsum, nblk);
    scan_c_k<<<nblk, 256, 0, stream>>>(rp_o, wo_o, bsum, N, E);
    scan_a_k<<<nblk, 256, 0, stream>>>(wo_s, rp_s, bsum, N);
    scan_b_k<<<1, 512, 0, stream>>>(bsum, nblk);
    scan_c_k<<<nblk, 256, 0, stream>>>(rp_s, wo_s, bsum, N, E);
    scatter_k<<<eblk, 256, 0, stream>>>(o_edges, o_vals, wo_o, csr_src_o, csr_val_o, E);
    scatter_k<<<eblk, 256, 0, stream>>>(s_edges, s_vals, wo_s, csr_src_s, csr_val_s, E);

    // ---- projection precompute ----
    prep_k<<<1, 128, 0, stream>>>(dec1_W, dec1_b, dec2_W, dec2_b,
                                  W_o2, b_o2, W_s2, b_s2, ag1, ag2,
                                  Mo, Ms, beta, cc);

    // ---- layer 1 GEMMs (both branches, one launch) ----
    dim3 ggrid((N + 127) / 128, 2);
    gemm2_k<<<ggrid, 256, 0, stream>>>(x, W_o1, W_s1, B0, B1, N);

    // ---- layer-1 SpMM + bias + relu + projection to 3 scalars (both) ----
    dim3 sgrid((N * 64 + 255) / 256, 2);
    seg_spmm_fused2_k<<<sgrid, 256, 0, stream>>>(rp_o, csr_src_o, csr_val_o, B0, b_o1, Mo, To,
                                                 rp_s, csr_src_s, csr_val_s, B1, b_s1, Ms, Ts, N);

    // ---- layer-2 scalar SpMM + gate ----
    gate_k<<<nblk, 256, 0, stream>>>(rp_o, csr_src_o, csr_val_o, To,
                                     rp_s, csr_src_s, csr_val_s, Ts,
                                     beta, av, bv, N);

    decode_k<<<(P + 255) / 256, 256, 0, stream>>>(idx, av, bv, cc, out, P);
}

// Round 7
// 695.830 us; speedup vs baseline: 12.3946x; 1.0703x over previous
//
#include <hip/hip_runtime.h>

// ---------------------------------------------------------------------------
// IGCN link prediction, round 6.
// - Layer-2 collapsed to scalars (R4), tiled GEMM (R5).
// - NEW: S1 stored as bf16 (RNE) -> halves the dominant SpMM gather stream.
// - NEW: unified CSR build: one histogram/scan/scatter over both graphs
//   (combined csr[2E]; graph-s row ptrs are rp2+N, already E-offset).
// ---------------------------------------------------------------------------

__device__ __forceinline__ float wave_sum64(float x) {
#pragma unroll
    for (int o = 32; o > 0; o >>= 1) x += __shfl_xor(x, o, 64);
    return x;
}

__device__ __forceinline__ unsigned short f2bf(float f) {  // round-nearest-even
    unsigned int u = __float_as_uint(f);
    u += 0x7FFF + ((u >> 16) & 1);
    return (unsigned short)(u >> 16);
}

__device__ __forceinline__ float2 bf2f2(unsigned int u) {  // 2 bf16 -> 2 f32
    float2 r;
    r.x = __uint_as_float(u << 16);          // low ushort = even col
    r.y = __uint_as_float(u & 0xFFFF0000u);  // high ushort = odd col
    return r;
}

// ---------------- unified CSR construction (both graphs) ----------------

__global__ __launch_bounds__(256) void hist2_k(const int* __restrict__ eo,
                                               const int* __restrict__ es,
                                               int* __restrict__ cnt2, int E, int N) {
    int e = blockIdx.x * 256 + threadIdx.x;
    if (e >= E) return;
    const int* edges = blockIdx.y ? es : eo;
    atomicAdd(&cnt2[blockIdx.y * N + edges[e]], 1);
}

__global__ __launch_bounds__(256) void scan_a_k(const int* __restrict__ cnt,
                                                int* __restrict__ exc,
                                                int* __restrict__ bsum, int n) {
    __shared__ int sh[256];
    int tid = threadIdx.x;
    int i = blockIdx.x * 256 + tid;
    int v = (i < n) ? cnt[i] : 0;
    sh[tid] = v;
    __syncthreads();
#pragma unroll
    for (int o = 1; o < 256; o <<= 1) {
        int t = (tid >= o) ? sh[tid - o] : 0;
        __syncthreads();
        sh[tid] += t;
        __syncthreads();
    }
    if (i < n) exc[i] = sh[tid] - v;
    if (tid == 255) bsum[blockIdx.x] = sh[tid];
}

__global__ __launch_bounds__(1024) void scan_b_k(int* __restrict__ bsum, int nblk) {
    __shared__ int sh[1024];
    int t = threadIdx.x;
    int v = (t < nblk) ? bsum[t] : 0;
    sh[t] = v;
    __syncthreads();
#pragma unroll
    for (int o = 1; o < 1024; o <<= 1) {
        int tv = (t >= o) ? sh[t - o] : 0;
        __syncthreads();
        sh[t] += tv;
        __syncthreads();
    }
    if (t < nblk) bsum[t] = sh[t] - v;
}

__global__ __launch_bounds__(256) void scan_c_k(int* __restrict__ rp,
                                                int* __restrict__ wo,
                                                const int* __restrict__ bsum,
                                                int n, int total) {
    int i = blockIdx.x * 256 + threadIdx.x;
    if (i < n) {
        int v = rp[i] + bsum[blockIdx.x];
        rp[i] = v;
        wo[i] = v;
    }
    if (i == 0) rp[n] = total;
}

__global__ __launch_bounds__(256) void scatter2_k(const int* __restrict__ eo,
                                                  const float* __restrict__ vo,
                                                  const int* __restrict__ es,
                                                  const float* __restrict__ vs,
                                                  int* __restrict__ wo2,
                                                  int* __restrict__ csr_src,
                                                  float* __restrict__ csr_val,
                                                  int E, int N) {
    int e = blockIdx.x * 256 + threadIdx.x;
    if (e >= E) return;
    const int* edges = blockIdx.y ? es : eo;
    const float* vals = blockIdx.y ? vs : vo;
    int dst = edges[e];
    int pos = atomicAdd(&wo2[blockIdx.y * N + dst], 1);
    csr_src[pos] = edges[E + e];
    csr_val[pos] = vals[e];
}

// ---------------- precompute projections ----------------
__global__ void prep_k(const float* __restrict__ dec1_W, const float* __restrict__ dec1_b,
                       const float* __restrict__ dec2_W, const float* __restrict__ dec2_b,
                       const float* __restrict__ W_o2, const float* __restrict__ b_o2,
                       const float* __restrict__ W_s2, const float* __restrict__ b_s2,
                       const float* __restrict__ ag1, const float* __restrict__ ag2,
                       float* __restrict__ Mo, float* __restrict__ Ms,
                       float* __restrict__ beta, float* __restrict__ cc) {
    __shared__ float vsh[128];
    int t = threadIdx.x;  // 128 threads
    float s = 0.f;
    for (int j = 0; j < 64; ++j) s += dec1_W[t * 64 + j] * dec2_W[j];
    vsh[t] = s;
    __syncthreads();
    const float* vlo = vsh;
    const float* vhi = vsh + 64;
    float m0 = 0, m1 = 0, m2 = 0, n0 = 0, n1 = 0, n2 = 0;
    for (int k = 0; k < 64; ++k) {
        float wo = W_o2[t * 64 + k], wsv = W_s2[t * 64 + k];
        m0 += wo * ag1[k];  m1 += wo * vlo[k];  m2 += wo * vhi[k];
        n0 += wsv * ag2[k]; n1 += wsv * vlo[k]; n2 += wsv * vhi[k];
    }
    Mo[0 * 128 + t] = m0; Mo[1 * 128 + t] = m1; Mo[2 * 128 + t] = m2;
    Ms[0 * 128 + t] = n0; Ms[1 * 128 + t] = n1; Ms[2 * 128 + t] = n2;
    if (t == 0) {
        float b0 = 0, b1 = 0, b2 = 0, s0 = 0, s1 = 0, s2 = 0, c0 = 0;
        for (int k = 0; k < 64; ++k) {
            b0 += b_o2[k] * ag1[k]; b1 += b_o2[k] * vlo[k]; b2 += b_o2[k] * vhi[k];
            s0 += b_s2[k] * ag2[k]; s1 += b_s2[k] * vlo[k]; s2 += b_s2[k] * vhi[k];
            c0 += dec1_b[k] * dec2_W[k];
        }
        beta[0] = b0; beta[1] = b1; beta[2] = b2;
        beta[4] = s0; beta[5] = s1; beta[6] = s2;
        *cc = c0 + dec2_b[0];
    }
}

// ---------------- tiled f32 GEMM -> bf16 output, both branches ----------------
// S[b][n,128](bf16) = X[n,128] @ W[b][128,128].  128x128 C-tile, 16-wide K
// panels in LDS, 8x8 register tile per thread.
__global__ __launch_bounds__(256) void gemm2_k(const float* __restrict__ X,
                                               const float* __restrict__ W0,
                                               const float* __restrict__ W1,
                                               unsigned short* __restrict__ S0,
                                               unsigned short* __restrict__ S1,
                                               int nrows) {
    __shared__ __align__(16) float XL[128 * 17];
    __shared__ __align__(16) float WL[16 * 132];

    const float* W = (blockIdx.y == 0) ? W0 : W1;
    unsigned short* S = (blockIdx.y == 0) ? S0 : S1;

    const int tid = threadIdx.x;
    const int tx = tid & 15;
    const int ty = tid >> 4;
    const int row0 = blockIdx.x * 128;
    const int c0 = tx * 8;
    const int r0 = ty * 8;

    float acc[8][8];
#pragma unroll
    for (int i = 0; i < 8; ++i)
#pragma unroll
        for (int j = 0; j < 8; ++j) acc[i][j] = 0.f;

    const float4* X4 = (const float4*)X;
    const float4* W4 = (const float4*)W;

    for (int kp = 0; kp < 8; ++kp) {
        if (kp) __syncthreads();
#pragma unroll
        for (int it = 0; it < 2; ++it) {
            int f = it * 256 + tid;
            int r = f >> 2, kq = f & 3;
            int gr = row0 + r;
            if (gr >= nrows) gr = nrows - 1;
            float4 v = X4[(size_t)gr * 32 + kp * 4 + kq];
            int base = r * 17 + kq * 4;
            XL[base + 0] = v.x; XL[base + 1] = v.y;
            XL[base + 2] = v.z; XL[base + 3] = v.w;
        }
#pragma unroll
        for (int it = 0; it < 2; ++it) {
            int f = it * 256 + tid;
            int kk = f >> 5, cq = f & 31;
            float4 v = W4[(size_t)(kp * 16 + kk) * 32 + cq];
            *(float4*)&WL[kk * 132 + cq * 4] = v;
        }
        __syncthreads();

#pragma unroll 4
        for (int kk = 0; kk < 16; ++kk) {
            float xr[8];
#pragma unroll
            for (int i = 0; i < 8; ++i) xr[i] = XL[(r0 + i) * 17 + kk];
            float4 wa = *(const float4*)&WL[kk * 132 + c0];
            float4 wb = *(const float4*)&WL[kk * 132 + c0 + 4];
            float wv[8] = {wa.x, wa.y, wa.z, wa.w, wb.x, wb.y, wb.z, wb.w};
#pragma unroll
            for (int i = 0; i < 8; ++i)
#pragma unroll
                for (int j = 0; j < 8; ++j) acc[i][j] += xr[i] * wv[j];
        }
    }

#pragma unroll
    for (int i = 0; i < 8; ++i) {
        int gr = row0 + r0 + i;
        if (gr < nrows) {
            union { unsigned short h[8]; uint4 u4; } p;
#pragma unroll
            for (int j = 0; j < 8; ++j) p.h[j] = f2bf(acc[i][j]);
            ((uint4*)S)[(size_t)gr * 16 + tx] = p.u4;  // 8 bf16 = 16 B
        }
    }
}

// ------- layer-1 gather SpMM (bf16 rows) + bias + relu + 3-way projection ----
// both branches via blockIdx.y; one wave per node; lane = 2 cols (one u32).
__global__ __launch_bounds__(256) void seg_spmm_fused2_k(
    const int* __restrict__ rp2, const int* __restrict__ csr_src,
    const float* __restrict__ csr_val,
    const unsigned short* __restrict__ So, const unsigned short* __restrict__ Ss,
    const float* __restrict__ bias_o, const float* __restrict__ bias_s,
    const float* __restrict__ Mo, const float* __restrict__ Ms,
    float4* __restrict__ To, float4* __restrict__ Ts, int n) {
    const int* rp;
    const unsigned int* S;
    const float* bias;
    const float* M;
    float4* T;
    if (blockIdx.y == 0) {
        rp = rp2;     S = (const unsigned int*)So; bias = bias_o; M = Mo; T = To;
    } else {
        rp = rp2 + n; S = (const unsigned int*)Ss; bias = bias_s; M = Ms; T = Ts;
    }
    int wid = (blockIdx.x * 256 + threadIdx.x) >> 6;
    int lane = threadIdx.x & 63;
    if (wid >= n) return;
    int e = rp[wid], end = rp[wid + 1];
    float ax = 0.f, ay = 0.f;
    for (; e + 3 < end; e += 4) {
        int s0 = csr_src[e], s1 = csr_src[e + 1], s2 = csr_src[e + 2], s3 = csr_src[e + 3];
        float v0 = csr_val[e], v1 = csr_val[e + 1], v2 = csr_val[e + 2], v3 = csr_val[e + 3];
        float2 m0 = bf2f2(S[s0 * 64 + lane]);
        float2 m1 = bf2f2(S[s1 * 64 + lane]);
        float2 m2 = bf2f2(S[s2 * 64 + lane]);
        float2 m3 = bf2f2(S[s3 * 64 + lane]);
        ax += m0.x * v0 + m1.x * v1 + m2.x * v2 + m3.x * v3;
        ay += m0.y * v0 + m1.y * v1 + m2.y * v2 + m3.y * v3;
    }
    for (; e < end; ++e) {
        float2 m = bf2f2(S[csr_src[e] * 64 + lane]);
        float v = csr_val[e];
        ax += m.x * v;
        ay += m.y * v;
    }
    float2 bb = ((const float2*)bias)[lane];
    ax = fmaxf(ax + bb.x, 0.f);
    ay = fmaxf(ay + bb.y, 0.f);
    float2 M0 = ((const float2*)(M + 0 * 128))[lane];
    float2 M1 = ((const float2*)(M + 1 * 128))[lane];
    float2 M2 = ((const float2*)(M + 2 * 128))[lane];
    float d = wave_sum64(ax * M0.x + ay * M0.y);
    float u = wave_sum64(ax * M1.x + ay * M1.y);
    float w = wave_sum64(ax * M2.x + ay * M2.y);
    if (lane == 0) T[wid] = make_float4(d, u, w, 0.f);
}

// ------- layer-2 scalar SpMM (both graphs) + gate + decode projections -------
__global__ __launch_bounds__(256) void gate_k(
    const int* __restrict__ rp2, const int* __restrict__ csr_src,
    const float* __restrict__ csr_val,
    const float4* __restrict__ To, const float4* __restrict__ Ts,
    const float* __restrict__ beta,
    float* __restrict__ a, float* __restrict__ b, int n) {
    int i = blockIdx.x * 256 + threadIdx.x;
    if (i >= n) return;
    float d1 = 0.f, u1 = 0.f, w1 = 0.f;
    {
        int e = rp2[i], end = rp2[i + 1];
        for (; e + 3 < end; e += 4) {
            float4 t0 = To[csr_src[e]];
            float4 t1 = To[csr_src[e + 1]];
            float4 t2 = To[csr_src[e + 2]];
            float4 t3 = To[csr_src[e + 3]];
            float v0 = csr_val[e], v1 = csr_val[e + 1], v2 = csr_val[e + 2], v3 = csr_val[e + 3];
            d1 += t0.x * v0 + t1.x * v1 + t2.x * v2 + t3.x * v3;
            u1 += t0.y * v0 + t1.y * v1 + t2.y * v2 + t3.y * v3;
            w1 += t0.z * v0 + t1.z * v1 + t2.z * v2 + t3.z * v3;
        }
        for (; e < end; ++e) {
            float4 t = To[csr_src[e]];
            float v = csr_val[e];
            d1 += t.x * v; u1 += t.y * v; w1 += t.z * v;
        }
    }
    float d2 = 0.f, u2 = 0.f, w2 = 0.f;
    {
        int e = rp2[n + i], end = rp2[n + i + 1];
        for (; e + 3 < end; e += 4) {
            float4 t0 = Ts[csr_src[e]];
            float4 t1 = Ts[csr_src[e + 1]];
            float4 t2 = Ts[csr_src[e + 2]];
            float4 t3 = Ts[csr_src[e + 3]];
            float v0 = csr_val[e], v1 = csr_val[e + 1], v2 = csr_val[e + 2], v3 = csr_val[e + 3];
            d2 += t0.x * v0 + t1.x * v1 + t2.x * v2 + t3.x * v3;
            u2 += t0.y * v0 + t1.y * v1 + t2.y * v2 + t3.y * v3;
            w2 += t0.z * v0 + t1.z * v1 + t2.z * v2 + t3.z * v3;
        }
        for (; e < end; ++e) {
            float4 t = Ts[csr_src[e]];
            float v = csr_val[e];
            d2 += t.x * v; u2 += t.y * v; w2 += t.z * v;
        }
    }
    d1 += beta[0]; u1 += beta[1]; w1 += beta[2];
    d2 += beta[4]; u2 += beta[5]; w2 += beta[6];
    a[i] = d1 * u1 + d2 * u2;
    b[i] = d1 * w1 + d2 * w2;
}

__global__ __launch_bounds__(256) void decode_k(const int* __restrict__ idx,
                                                const float* __restrict__ a,
                                                const float* __restrict__ b,
                                                const float* __restrict__ c,
                                                float* __restrict__ out, int P) {
    int i = blockIdx.x * 256 + threadIdx.x;
    if (i >= P) return;
    out[i] = a[idx[i]] + b[idx[P + i]] + *c;
}

// ---------------------------------------------------------------------------

extern "C" void kernel_launch(void* const* d_in, const int* in_sizes, int n_in,
                              void* d_out, int out_size, void* d_ws, size_t ws_size,
                              hipStream_t stream) {
    const float* x      = (const float*)d_in[0];
    const int*   o_edges= (const int*)d_in[1];
    const float* o_vals = (const float*)d_in[2];
    const int*   s_edges= (const int*)d_in[3];
    const float* s_vals = (const float*)d_in[4];
    const int*   idx    = (const int*)d_in[5];
    const float* W_o1   = (const float*)d_in[6];
    const float* b_o1   = (const float*)d_in[7];
    const float* W_o2   = (const float*)d_in[8];
    const float* b_o2   = (const float*)d_in[9];
    const float* W_s1   = (const float*)d_in[10];
    const float* b_s1   = (const float*)d_in[11];
    const float* W_s2   = (const float*)d_in[12];
    const float* b_s2   = (const float*)d_in[13];
    const float* ag1    = (const float*)d_in[14];
    const float* ag2    = (const float*)d_in[15];
    const float* dec1_W = (const float*)d_in[16];
    const float* dec1_b = (const float*)d_in[17];
    const float* dec2_W = (const float*)d_in[18];
    const float* dec2_b = (const float*)d_in[19];
    float* out = (float*)d_out;

    const int N = in_sizes[0] / 128;
    const int E = in_sizes[1] / 2;
    const int P = out_size;

    const size_t NBH = (size_t)N * 128 * 2;  // [N,128] bf16 bytes

    char* ws = (char*)d_ws;
    size_t off = 0;
    auto alloc = [&](size_t bytes) {
        char* p = ws + off;
        off += (bytes + 255) & ~(size_t)255;
        return p;
    };

    unsigned short* B0 = (unsigned short*)alloc(NBH);  // S1o (bf16)
    unsigned short* B1 = (unsigned short*)alloc(NBH);  // S1s (bf16)
    float4* To = (float4*)alloc((size_t)N * 16);
    float4* Ts = (float4*)alloc((size_t)N * 16);
    float* av = (float*)alloc((size_t)P * 4);
    float* bv = (float*)alloc((size_t)P * 4);
    float* Mo = (float*)alloc(3 * 128 * 4);
    float* Ms = (float*)alloc(3 * 128 * 4);
    float* beta = (float*)alloc(32);
    float* cc = (float*)alloc(16);
    int* cnt2 = (int*)alloc((size_t)2 * N * 4);       // histogram/write cursors
    int* rp2  = (int*)alloc((size_t)(2 * N + 1) * 4); // combined row ptrs
    int* csr_src = (int*)alloc((size_t)2 * E * 4);    // combined CSR
    float* csr_val = (float*)alloc((size_t)2 * E * 4);
    int* bsum = (int*)alloc(1024 * 4);

    const int nblk  = (N + 255) / 256;
    const int nblk2 = (2 * N + 255) / 256;  // 782 <= 1024
    const int eblk  = (E + 255) / 256;

    // ---- unified CSR build ----
    hipMemsetAsync(cnt2, 0, (size_t)2 * N * 4, stream);
    dim3 hgrid(eblk, 2);
    hist2_k<<<hgrid, 256, 0, stream>>>(o_edges, s_edges, cnt2, E, N);
    scan_a_k<<<nblk2, 256, 0, stream>>>(cnt2, rp2, bsum, 2 * N);
    scan_b_k<<<1, 1024, 0, stream>>>(bsum, nblk2);
    scan_c_k<<<nblk2, 256, 0, stream>>>(rp2, cnt2, bsum, 2 * N, 2 * E);
    scatter2_k<<<hgrid, 256, 0, stream>>>(o_edges, o_vals, s_edges, s_vals,
                                          cnt2, csr_src, csr_val, E, N);

    // ---- projection precompute ----
    prep_k<<<1, 128, 0, stream>>>(dec1_W, dec1_b, dec2_W, dec2_b,
                                  W_o2, b_o2, W_s2, b_s2, ag1, ag2,
                                  Mo, Ms, beta, cc);

    // ---- layer 1 GEMMs (both branches, bf16 output) ----
    dim3 ggrid((N + 127) / 128, 2);
    gemm2_k<<<ggrid, 256, 0, stream>>>(x, W_o1, W_s1, B0, B1, N);

    // ---- layer-1 SpMM + bias + relu + projection to 3 scalars (both) ----
    dim3 sgrid((N * 64 + 255) / 256, 2);
    seg_spmm_fused2_k<<<sgrid, 256, 0, stream>>>(rp2, csr_src, csr_val,
                                                 B0, B1, b_o1, b_s1, Mo, Ms,
                                                 To, Ts, N);

    // ---- layer-2 scalar SpMM + gate ----
    gate_k<<<nblk, 256, 0, stream>>>(rp2, csr_src, csr_val, To, Ts, beta, av, bv, N);

    decode_k<<<(P + 255) / 256, 256, 0, stream>>>(idx, av, bv, cc, out, P);
}

// Round 8
// 656.975 us; speedup vs baseline: 13.1277x; 1.0591x over previous
//
#include <hip/hip_runtime.h>

// ---------------------------------------------------------------------------
// IGCN link prediction, round 7.
// - Layer-2 collapsed to scalars (R4), tiled GEMM (R5), bf16 S1 (R6).
// - NEW: packed CSR records {src, val} as int2 -> single 8B store per edge
//   in scatter (was 2 random 4B stores = 2 dirty lines, 306MB HBM writes).
// - NEW: seg_spmm gather loop unrolled x8 for deeper MLP.
// ---------------------------------------------------------------------------

__device__ __forceinline__ float wave_sum64(float x) {
#pragma unroll
    for (int o = 32; o > 0; o >>= 1) x += __shfl_xor(x, o, 64);
    return x;
}

__device__ __forceinline__ unsigned short f2bf(float f) {  // round-nearest-even
    unsigned int u = __float_as_uint(f);
    u += 0x7FFF + ((u >> 16) & 1);
    return (unsigned short)(u >> 16);
}

__device__ __forceinline__ float2 bf2f2(unsigned int u) {  // 2 bf16 -> 2 f32
    float2 r;
    r.x = __uint_as_float(u << 16);
    r.y = __uint_as_float(u & 0xFFFF0000u);
    return r;
}

// ---------------- unified CSR construction (both graphs) ----------------

__global__ __launch_bounds__(256) void hist2_k(const int* __restrict__ eo,
                                               const int* __restrict__ es,
                                               int* __restrict__ cnt2, int E, int N) {
    int e = blockIdx.x * 256 + threadIdx.x;
    if (e >= E) return;
    const int* edges = blockIdx.y ? es : eo;
    atomicAdd(&cnt2[blockIdx.y * N + edges[e]], 1);
}

__global__ __launch_bounds__(256) void scan_a_k(const int* __restrict__ cnt,
                                                int* __restrict__ exc,
                                                int* __restrict__ bsum, int n) {
    __shared__ int sh[256];
    int tid = threadIdx.x;
    int i = blockIdx.x * 256 + tid;
    int v = (i < n) ? cnt[i] : 0;
    sh[tid] = v;
    __syncthreads();
#pragma unroll
    for (int o = 1; o < 256; o <<= 1) {
        int t = (tid >= o) ? sh[tid - o] : 0;
        __syncthreads();
        sh[tid] += t;
        __syncthreads();
    }
    if (i < n) exc[i] = sh[tid] - v;
    if (tid == 255) bsum[blockIdx.x] = sh[tid];
}

__global__ __launch_bounds__(1024) void scan_b_k(int* __restrict__ bsum, int nblk) {
    __shared__ int sh[1024];
    int t = threadIdx.x;
    int v = (t < nblk) ? bsum[t] : 0;
    sh[t] = v;
    __syncthreads();
#pragma unroll
    for (int o = 1; o < 1024; o <<= 1) {
        int tv = (t >= o) ? sh[t - o] : 0;
        __syncthreads();
        sh[t] += tv;
        __syncthreads();
    }
    if (t < nblk) bsum[t] = sh[t] - v;
}

__global__ __launch_bounds__(256) void scan_c_k(int* __restrict__ rp,
                                                int* __restrict__ wo,
                                                const int* __restrict__ bsum,
                                                int n, int total) {
    int i = blockIdx.x * 256 + threadIdx.x;
    if (i < n) {
        int v = rp[i] + bsum[blockIdx.x];
        rp[i] = v;
        wo[i] = v;
    }
    if (i == 0) rp[n] = total;
}

// scatter edges into CSR buckets: ONE packed 8B record per edge
__global__ __launch_bounds__(256) void scatter2_k(const int* __restrict__ eo,
                                                  const float* __restrict__ vo,
                                                  const int* __restrict__ es,
                                                  const float* __restrict__ vs,
                                                  int* __restrict__ wo2,
                                                  int2* __restrict__ csr,
                                                  int E, int N) {
    int e = blockIdx.x * 256 + threadIdx.x;
    if (e >= E) return;
    const int* edges = blockIdx.y ? es : eo;
    const float* vals = blockIdx.y ? vs : vo;
    int dst = edges[e];
    int pos = atomicAdd(&wo2[blockIdx.y * N + dst], 1);
    csr[pos] = make_int2(edges[E + e], __float_as_int(vals[e]));
}

// ---------------- precompute projections ----------------
__global__ void prep_k(const float* __restrict__ dec1_W, const float* __restrict__ dec1_b,
                       const float* __restrict__ dec2_W, const float* __restrict__ dec2_b,
                       const float* __restrict__ W_o2, const float* __restrict__ b_o2,
                       const float* __restrict__ W_s2, const float* __restrict__ b_s2,
                       const float* __restrict__ ag1, const float* __restrict__ ag2,
                       float* __restrict__ Mo, float* __restrict__ Ms,
                       float* __restrict__ beta, float* __restrict__ cc) {
    __shared__ float vsh[128];
    int t = threadIdx.x;  // 128 threads
    float s = 0.f;
    for (int j = 0; j < 64; ++j) s += dec1_W[t * 64 + j] * dec2_W[j];
    vsh[t] = s;
    __syncthreads();
    const float* vlo = vsh;
    const float* vhi = vsh + 64;
    float m0 = 0, m1 = 0, m2 = 0, n0 = 0, n1 = 0, n2 = 0;
    for (int k = 0; k < 64; ++k) {
        float wo = W_o2[t * 64 + k], wsv = W_s2[t * 64 + k];
        m0 += wo * ag1[k];  m1 += wo * vlo[k];  m2 += wo * vhi[k];
        n0 += wsv * ag2[k]; n1 += wsv * vlo[k]; n2 += wsv * vhi[k];
    }
    Mo[0 * 128 + t] = m0; Mo[1 * 128 + t] = m1; Mo[2 * 128 + t] = m2;
    Ms[0 * 128 + t] = n0; Ms[1 * 128 + t] = n1; Ms[2 * 128 + t] = n2;
    if (t == 0) {
        float b0 = 0, b1 = 0, b2 = 0, s0 = 0, s1 = 0, s2 = 0, c0 = 0;
        for (int k = 0; k < 64; ++k) {
            b0 += b_o2[k] * ag1[k]; b1 += b_o2[k] * vlo[k]; b2 += b_o2[k] * vhi[k];
            s0 += b_s2[k] * ag2[k]; s1 += b_s2[k] * vlo[k]; s2 += b_s2[k] * vhi[k];
            c0 += dec1_b[k] * dec2_W[k];
        }
        beta[0] = b0; beta[1] = b1; beta[2] = b2;
        beta[4] = s0; beta[5] = s1; beta[6] = s2;
        *cc = c0 + dec2_b[0];
    }
}

// ---------------- tiled f32 GEMM -> bf16 output, both branches ----------------
__global__ __launch_bounds__(256) void gemm2_k(const float* __restrict__ X,
                                               const float* __restrict__ W0,
                                               const float* __restrict__ W1,
                                               unsigned short* __restrict__ S0,
                                               unsigned short* __restrict__ S1,
                                               int nrows) {
    __shared__ __align__(16) float XL[128 * 17];
    __shared__ __align__(16) float WL[16 * 132];

    const float* W = (blockIdx.y == 0) ? W0 : W1;
    unsigned short* S = (blockIdx.y == 0) ? S0 : S1;

    const int tid = threadIdx.x;
    const int tx = tid & 15;
    const int ty = tid >> 4;
    const int row0 = blockIdx.x * 128;
    const int c0 = tx * 8;
    const int r0 = ty * 8;

    float acc[8][8];
#pragma unroll
    for (int i = 0; i < 8; ++i)
#pragma unroll
        for (int j = 0; j < 8; ++j) acc[i][j] = 0.f;

    const float4* X4 = (const float4*)X;
    const float4* W4 = (const float4*)W;

    for (int kp = 0; kp < 8; ++kp) {
        if (kp) __syncthreads();
#pragma unroll
        for (int it = 0; it < 2; ++it) {
            int f = it * 256 + tid;
            int r = f >> 2, kq = f & 3;
            int gr = row0 + r;
            if (gr >= nrows) gr = nrows - 1;
            float4 v = X4[(size_t)gr * 32 + kp * 4 + kq];
            int base = r * 17 + kq * 4;
            XL[base + 0] = v.x; XL[base + 1] = v.y;
            XL[base + 2] = v.z; XL[base + 3] = v.w;
        }
#pragma unroll
        for (int it = 0; it < 2; ++it) {
            int f = it * 256 + tid;
            int kk = f >> 5, cq = f & 31;
            float4 v = W4[(size_t)(kp * 16 + kk) * 32 + cq];
            *(float4*)&WL[kk * 132 + cq * 4] = v;
        }
        __syncthreads();

#pragma unroll 4
        for (int kk = 0; kk < 16; ++kk) {
            float xr[8];
#pragma unroll
            for (int i = 0; i < 8; ++i) xr[i] = XL[(r0 + i) * 17 + kk];
            float4 wa = *(const float4*)&WL[kk * 132 + c0];
            float4 wb = *(const float4*)&WL[kk * 132 + c0 + 4];
            float wv[8] = {wa.x, wa.y, wa.z, wa.w, wb.x, wb.y, wb.z, wb.w};
#pragma unroll
            for (int i = 0; i < 8; ++i)
#pragma unroll
                for (int j = 0; j < 8; ++j) acc[i][j] += xr[i] * wv[j];
        }
    }

#pragma unroll
    for (int i = 0; i < 8; ++i) {
        int gr = row0 + r0 + i;
        if (gr < nrows) {
            union { unsigned short h[8]; uint4 u4; } p;
#pragma unroll
            for (int j = 0; j < 8; ++j) p.h[j] = f2bf(acc[i][j]);
            ((uint4*)S)[(size_t)gr * 16 + tx] = p.u4;
        }
    }
}

// ------- layer-1 gather SpMM (bf16 rows) + bias + relu + 3-way projection ----
// both branches via blockIdx.y; one wave per node; lane = 2 cols (one u32);
// packed CSR records; gather loop unrolled x8 (+x4 tail).
__global__ __launch_bounds__(256) void seg_spmm_fused2_k(
    const int* __restrict__ rp2, const int2* __restrict__ csr,
    const unsigned short* __restrict__ So, const unsigned short* __restrict__ Ss,
    const float* __restrict__ bias_o, const float* __restrict__ bias_s,
    const float* __restrict__ Mo, const float* __restrict__ Ms,
    float4* __restrict__ To, float4* __restrict__ Ts, int n) {
    const int* rp;
    const unsigned int* S;
    const float* bias;
    const float* M;
    float4* T;
    if (blockIdx.y == 0) {
        rp = rp2;     S = (const unsigned int*)So; bias = bias_o; M = Mo; T = To;
    } else {
        rp = rp2 + n; S = (const unsigned int*)Ss; bias = bias_s; M = Ms; T = Ts;
    }
    int wid = (blockIdx.x * 256 + threadIdx.x) >> 6;
    int lane = threadIdx.x & 63;
    if (wid >= n) return;
    int e = rp[wid], end = rp[wid + 1];
    float ax = 0.f, ay = 0.f;
    for (; e + 7 < end; e += 8) {
        int2 c0 = csr[e],     c1 = csr[e + 1], c2 = csr[e + 2], c3 = csr[e + 3];
        int2 c4 = csr[e + 4], c5 = csr[e + 5], c6 = csr[e + 6], c7 = csr[e + 7];
        float2 m0 = bf2f2(S[c0.x * 64 + lane]);
        float2 m1 = bf2f2(S[c1.x * 64 + lane]);
        float2 m2 = bf2f2(S[c2.x * 64 + lane]);
        float2 m3 = bf2f2(S[c3.x * 64 + lane]);
        float2 m4 = bf2f2(S[c4.x * 64 + lane]);
        float2 m5 = bf2f2(S[c5.x * 64 + lane]);
        float2 m6 = bf2f2(S[c6.x * 64 + lane]);
        float2 m7 = bf2f2(S[c7.x * 64 + lane]);
        float v0 = __int_as_float(c0.y), v1 = __int_as_float(c1.y);
        float v2 = __int_as_float(c2.y), v3 = __int_as_float(c3.y);
        float v4 = __int_as_float(c4.y), v5 = __int_as_float(c5.y);
        float v6 = __int_as_float(c6.y), v7 = __int_as_float(c7.y);
        ax += m0.x * v0 + m1.x * v1 + m2.x * v2 + m3.x * v3;
        ay += m0.y * v0 + m1.y * v1 + m2.y * v2 + m3.y * v3;
        ax += m4.x * v4 + m5.x * v5 + m6.x * v6 + m7.x * v7;
        ay += m4.y * v4 + m5.y * v5 + m6.y * v6 + m7.y * v7;
    }
    for (; e + 3 < end; e += 4) {
        int2 c0 = csr[e], c1 = csr[e + 1], c2 = csr[e + 2], c3 = csr[e + 3];
        float2 m0 = bf2f2(S[c0.x * 64 + lane]);
        float2 m1 = bf2f2(S[c1.x * 64 + lane]);
        float2 m2 = bf2f2(S[c2.x * 64 + lane]);
        float2 m3 = bf2f2(S[c3.x * 64 + lane]);
        float v0 = __int_as_float(c0.y), v1 = __int_as_float(c1.y);
        float v2 = __int_as_float(c2.y), v3 = __int_as_float(c3.y);
        ax += m0.x * v0 + m1.x * v1 + m2.x * v2 + m3.x * v3;
        ay += m0.y * v0 + m1.y * v1 + m2.y * v2 + m3.y * v3;
    }
    for (; e < end; ++e) {
        int2 c = csr[e];
        float2 m = bf2f2(S[c.x * 64 + lane]);
        float v = __int_as_float(c.y);
        ax += m.x * v;
        ay += m.y * v;
    }
    float2 bb = ((const float2*)bias)[lane];
    ax = fmaxf(ax + bb.x, 0.f);
    ay = fmaxf(ay + bb.y, 0.f);
    float2 M0 = ((const float2*)(M + 0 * 128))[lane];
    float2 M1 = ((const float2*)(M + 1 * 128))[lane];
    float2 M2 = ((const float2*)(M + 2 * 128))[lane];
    float d = wave_sum64(ax * M0.x + ay * M0.y);
    float u = wave_sum64(ax * M1.x + ay * M1.y);
    float w = wave_sum64(ax * M2.x + ay * M2.y);
    if (lane == 0) T[wid] = make_float4(d, u, w, 0.f);
}

// ------- layer-2 scalar SpMM (both graphs) + gate + decode projections -------
__global__ __launch_bounds__(256) void gate_k(
    const int* __restrict__ rp2, const int2* __restrict__ csr,
    const float4* __restrict__ To, const float4* __restrict__ Ts,
    const float* __restrict__ beta,
    float* __restrict__ a, float* __restrict__ b, int n) {
    int i = blockIdx.x * 256 + threadIdx.x;
    if (i >= n) return;
    float d1 = 0.f, u1 = 0.f, w1 = 0.f;
    {
        int e = rp2[i], end = rp2[i + 1];
        for (; e + 3 < end; e += 4) {
            int2 c0 = csr[e], c1 = csr[e + 1], c2 = csr[e + 2], c3 = csr[e + 3];
            float4 t0 = To[c0.x];
            float4 t1 = To[c1.x];
            float4 t2 = To[c2.x];
            float4 t3 = To[c3.x];
            float v0 = __int_as_float(c0.y), v1 = __int_as_float(c1.y);
            float v2 = __int_as_float(c2.y), v3 = __int_as_float(c3.y);
            d1 += t0.x * v0 + t1.x * v1 + t2.x * v2 + t3.x * v3;
            u1 += t0.y * v0 + t1.y * v1 + t2.y * v2 + t3.y * v3;
            w1 += t0.z * v0 + t1.z * v1 + t2.z * v2 + t3.z * v3;
        }
        for (; e < end; ++e) {
            int2 c = csr[e];
            float4 t = To[c.x];
            float v = __int_as_float(c.y);
            d1 += t.x * v; u1 += t.y * v; w1 += t.z * v;
        }
    }
    float d2 = 0.f, u2 = 0.f, w2 = 0.f;
    {
        int e = rp2[n + i], end = rp2[n + i + 1];
        for (; e + 3 < end; e += 4) {
            int2 c0 = csr[e], c1 = csr[e + 1], c2 = csr[e + 2], c3 = csr[e + 3];
            float4 t0 = Ts[c0.x];
            float4 t1 = Ts[c1.x];
            float4 t2 = Ts[c2.x];
            float4 t3 = Ts[c3.x];
            float v0 = __int_as_float(c0.y), v1 = __int_as_float(c1.y);
            float v2 = __int_as_float(c2.y), v3 = __int_as_float(c3.y);
            d2 += t0.x * v0 + t1.x * v1 + t2.x * v2 + t3.x * v3;
            u2 += t0.y * v0 + t1.y * v1 + t2.y * v2 + t3.y * v3;
            w2 += t0.z * v0 + t1.z * v1 + t2.z * v2 + t3.z * v3;
        }
        for (; e < end; ++e) {
            int2 c = csr[e];
            float4 t = Ts[c.x];
            float v = __int_as_float(c.y);
            d2 += t.x * v; u2 += t.y * v; w2 += t.z * v;
        }
    }
    d1 += beta[0]; u1 += beta[1]; w1 += beta[2];
    d2 += beta[4]; u2 += beta[5]; w2 += beta[6];
    a[i] = d1 * u1 + d2 * u2;
    b[i] = d1 * w1 + d2 * w2;
}

__global__ __launch_bounds__(256) void decode_k(const int* __restrict__ idx,
                                                const float* __restrict__ a,
                                                const float* __restrict__ b,
                                                const float* __restrict__ c,
                                                float* __restrict__ out, int P) {
    int i = blockIdx.x * 256 + threadIdx.x;
    if (i >= P) return;
    out[i] = a[idx[i]] + b[idx[P + i]] + *c;
}

// ---------------------------------------------------------------------------

extern "C" void kernel_launch(void* const* d_in, const int* in_sizes, int n_in,
                              void* d_out, int out_size, void* d_ws, size_t ws_size,
                              hipStream_t stream) {
    const float* x      = (const float*)d_in[0];
    const int*   o_edges= (const int*)d_in[1];
    const float* o_vals = (const float*)d_in[2];
    const int*   s_edges= (const int*)d_in[3];
    const float* s_vals = (const float*)d_in[4];
    const int*   idx    = (const int*)d_in[5];
    const float* W_o1   = (const float*)d_in[6];
    const float* b_o1   = (const float*)d_in[7];
    const float* W_o2   = (const float*)d_in[8];
    const float* b_o2   = (const float*)d_in[9];
    const float* W_s1   = (const float*)d_in[10];
    const float* b_s1   = (const float*)d_in[11];
    const float* W_s2   = (const float*)d_in[12];
    const float* b_s2   = (const float*)d_in[13];
    const float* ag1    = (const float*)d_in[14];
    const float* ag2    = (const float*)d_in[15];
    const float* dec1_W = (const float*)d_in[16];
    const float* dec1_b = (const float*)d_in[17];
    const float* dec2_W = (const float*)d_in[18];
    const float* dec2_b = (const float*)d_in[19];
    float* out = (float*)d_out;

    const int N = in_sizes[0] / 128;
    const int E = in_sizes[1] / 2;
    const int P = out_size;

    const size_t NBH = (size_t)N * 128 * 2;  // [N,128] bf16 bytes

    char* ws = (char*)d_ws;
    size_t off = 0;
    auto alloc = [&](size_t bytes) {
        char* p = ws + off;
        off += (bytes + 255) & ~(size_t)255;
        return p;
    };

    unsigned short* B0 = (unsigned short*)alloc(NBH);  // S1o (bf16)
    unsigned short* B1 = (unsigned short*)alloc(NBH);  // S1s (bf16)
    float4* To = (float4*)alloc((size_t)N * 16);
    float4* Ts = (float4*)alloc((size_t)N * 16);
    float* av = (float*)alloc((size_t)P * 4);
    float* bv = (float*)alloc((size_t)P * 4);
    float* Mo = (float*)alloc(3 * 128 * 4);
    float* Ms = (float*)alloc(3 * 128 * 4);
    float* beta = (float*)alloc(32);
    float* cc = (float*)alloc(16);
    int* cnt2 = (int*)alloc((size_t)2 * N * 4);       // histogram/write cursors
    int* rp2  = (int*)alloc((size_t)(2 * N + 1) * 4); // combined row ptrs
    int2* csr = (int2*)alloc((size_t)2 * E * 8);      // packed {src, val}
    int* bsum = (int*)alloc(1024 * 4);

    const int nblk  = (N + 255) / 256;
    const int nblk2 = (2 * N + 255) / 256;  // 782 <= 1024
    const int eblk  = (E + 255) / 256;

    // ---- unified CSR build ----
    hipMemsetAsync(cnt2, 0, (size_t)2 * N * 4, stream);
    dim3 hgrid(eblk, 2);
    hist2_k<<<hgrid, 256, 0, stream>>>(o_edges, s_edges, cnt2, E, N);
    scan_a_k<<<nblk2, 256, 0, stream>>>(cnt2, rp2, bsum, 2 * N);
    scan_b_k<<<1, 1024, 0, stream>>>(bsum, nblk2);
    scan_c_k<<<nblk2, 256, 0, stream>>>(rp2, cnt2, bsum, 2 * N, 2 * E);
    scatter2_k<<<hgrid, 256, 0, stream>>>(o_edges, o_vals, s_edges, s_vals,
                                          cnt2, csr, E, N);

    // ---- projection precompute ----
    prep_k<<<1, 128, 0, stream>>>(dec1_W, dec1_b, dec2_W, dec2_b,
                                  W_o2, b_o2, W_s2, b_s2, ag1, ag2,
                                  Mo, Ms, beta, cc);

    // ---- layer 1 GEMMs (both branches, bf16 output) ----
    dim3 ggrid((N + 127) / 128, 2);
    gemm2_k<<<ggrid, 256, 0, stream>>>(x, W_o1, W_s1, B0, B1, N);

    // ---- layer-1 SpMM + bias + relu + projection to 3 scalars (both) ----
    dim3 sgrid((N * 64 + 255) / 256, 2);
    seg_spmm_fused2_k<<<sgrid, 256, 0, stream>>>(rp2, csr, B0, B1, b_o1, b_s1,
                                                 Mo, Ms, To, Ts, N);

    // ---- layer-2 scalar SpMM + gate ----
    gate_k<<<nblk, 256, 0, stream>>>(rp2, csr, To, Ts, beta, av, bv, N);

    decode_k<<<(P + 255) / 256, 256, 0, stream>>>(idx, av, bv, cc, out, P);
}

// Round 9
// 368.364 us; speedup vs baseline: 23.4131x; 1.7835x over previous
//
#include <hip/hip_runtime.h>

// ---------------------------------------------------------------------------
// IGCN link prediction, round 8.
// - Layer-2 collapsed to scalars (R4), tiled GEMM (R5), bf16 S1 (R6),
//   packed CSR records (R7).
// - NEW: CSR build via two-level bucket sort (256-node buckets):
//   bhist (LDS hist) -> bscan -> bin (per-block contiguous runs, L2-local
//   writes) -> sort (per-bucket LDS sort, emits rp2 + final CSR coalesced).
//   Replaces the 263us random-scatter + per-node hist/scan (all XCD-L2
//   thrash: 200MB HBM writeback for a 25.6MB payload).
// ---------------------------------------------------------------------------

constexpr int BKT_SHIFT = 8;     // 256 nodes per bucket
constexpr int BKT_NODES = 256;
constexpr int SORT_CAP  = 7168;  // records/bucket LDS capacity (mean 4096, +48 sigma)

__device__ __forceinline__ float wave_sum64(float x) {
#pragma unroll
    for (int o = 32; o > 0; o >>= 1) x += __shfl_xor(x, o, 64);
    return x;
}

__device__ __forceinline__ unsigned short f2bf(float f) {  // round-nearest-even
    unsigned int u = __float_as_uint(f);
    u += 0x7FFF + ((u >> 16) & 1);
    return (unsigned short)(u >> 16);
}

__device__ __forceinline__ float2 bf2f2(unsigned int u) {  // 2 bf16 -> 2 f32
    float2 r;
    r.x = __uint_as_float(u << 16);
    r.y = __uint_as_float(u & 0xFFFF0000u);
    return r;
}

// ---------------- two-level bucket CSR build ----------------

// pass 0: coarse bucket histogram (LDS-staged)
__global__ __launch_bounds__(256) void bhist_k(const int* __restrict__ eo,
                                               const int* __restrict__ es,
                                               int* __restrict__ bcnt,
                                               int E, int N, int nb) {
    __shared__ int lh[1024];
    for (int i = threadIdx.x; i < nb; i += 256) lh[i] = 0;
    __syncthreads();
    int total = 2 * E;
    for (int t = blockIdx.x * 256 + threadIdx.x; t < total; t += gridDim.x * 256) {
        int g = (t >= E) ? 1 : 0;
        int e = g ? t - E : t;
        int dst = (g ? es : eo)[e];
        atomicAdd(&lh[(g * N + dst) >> BKT_SHIFT], 1);
    }
    __syncthreads();
    for (int i = threadIdx.x; i < nb; i += 256) {
        int v = lh[i];
        if (v) atomicAdd(&bcnt[i], v);
    }
}

// pass 0b: scan bucket counts -> bases + write cursors (nb <= 1024)
__global__ __launch_bounds__(1024) void bscan_k(const int* __restrict__ bcnt,
                                                int* __restrict__ bbase,
                                                int* __restrict__ bcur,
                                                int nb, int total) {
    __shared__ int sh[1024];
    int t = threadIdx.x;
    int v = (t < nb) ? bcnt[t] : 0;
    sh[t] = v;
    __syncthreads();
#pragma unroll
    for (int o = 1; o < 1024; o <<= 1) {
        int tv = (t >= o) ? sh[t - o] : 0;
        __syncthreads();
        sh[t] += tv;
        __syncthreads();
    }
    if (t < nb) {
        int b = sh[t] - v;
        bbase[t] = b;
        bcur[t] = b;
    }
    if (t == 0) bbase[nb] = total;
}

// pass 1: bin edges into coarse buckets, per-block contiguous runs.
// record: .x = (dst_local<<17) | src  (dst_local 8b, src 17b), .y = val bits
__global__ __launch_bounds__(256) void bin_k(const int* __restrict__ eo,
                                             const float* __restrict__ vo,
                                             const int* __restrict__ es,
                                             const float* __restrict__ vs,
                                             int* __restrict__ bcur,
                                             int2* __restrict__ binned,
                                             int E, int N, int nb, int chunk) {
    __shared__ int lcnt[1024];
    __shared__ int lbase[1024];
    int c0 = blockIdx.x * chunk;
    int c1 = min(c0 + chunk, 2 * E);
    for (int i = threadIdx.x; i < nb; i += 256) lcnt[i] = 0;
    __syncthreads();
    for (int t = c0 + threadIdx.x; t < c1; t += 256) {
        int g = (t >= E) ? 1 : 0;
        int e = g ? t - E : t;
        int dst = (g ? es : eo)[e];
        atomicAdd(&lcnt[(g * N + dst) >> BKT_SHIFT], 1);
    }
    __syncthreads();
    for (int i = threadIdx.x; i < nb; i += 256) {
        int v = lcnt[i];
        lbase[i] = v ? atomicAdd(&bcur[i], v) : 0;
        lcnt[i] = 0;  // reuse as local cursor
    }
    __syncthreads();
    for (int t = c0 + threadIdx.x; t < c1; t += 256) {
        int g = (t >= E) ? 1 : 0;
        int e = g ? t - E : t;
        const int* edges = g ? es : eo;
        int dst = edges[e];
        int dc = g * N + dst;
        int b = dc >> BKT_SHIFT;
        int pos = lbase[b] + atomicAdd(&lcnt[b], 1);
        int src = edges[E + e];
        float val = (g ? vs : vo)[e];
        binned[pos] = make_int2(((dc & (BKT_NODES - 1)) << 17) | src,
                                __float_as_int(val));
    }
}

// pass 2: per-bucket LDS sort by node; emits rp2 and final CSR (coalesced).
__global__ __launch_bounds__(256) void sort_k(const int* __restrict__ bbase,
                                              const int2* __restrict__ binned,
                                              int2* __restrict__ csr,
                                              int* __restrict__ rp2,
                                              int n2, int total) {
    __shared__ int2 lrec[SORT_CAP];
    __shared__ int ldeg[BKT_NODES];
    __shared__ int lsc[BKT_NODES];
    int b = blockIdx.x;
    int base = bbase[b];
    int count = min(bbase[b + 1] - base, SORT_CAP);
    int tid = threadIdx.x;
    for (int k = tid; k < count; k += 256) lrec[k] = binned[base + k];
    ldeg[tid] = 0;
    __syncthreads();
    for (int k = tid; k < count; k += 256) atomicAdd(&ldeg[lrec[k].x >> 17], 1);
    __syncthreads();
    int v = ldeg[tid];
    lsc[tid] = v;
    __syncthreads();
#pragma unroll
    for (int o = 1; o < 256; o <<= 1) {
        int tv = (tid >= o) ? lsc[tid - o] : 0;
        __syncthreads();
        lsc[tid] += tv;
        __syncthreads();
    }
    int excl = lsc[tid] - v;
    int node = b * BKT_NODES + tid;
    if (node < n2) rp2[node] = base + excl;
    if (b == 0 && tid == 0) rp2[n2] = total;
    ldeg[tid] = excl;  // reuse as scatter cursor
    __syncthreads();
    for (int k = tid; k < count; k += 256) {
        int2 r = lrec[k];
        int dl = r.x >> 17;
        int p = atomicAdd(&ldeg[dl], 1);
        csr[base + p] = make_int2(r.x & 0x1FFFF, r.y);
    }
}

// ---------------- precompute projections ----------------
__global__ void prep_k(const float* __restrict__ dec1_W, const float* __restrict__ dec1_b,
                       const float* __restrict__ dec2_W, const float* __restrict__ dec2_b,
                       const float* __restrict__ W_o2, const float* __restrict__ b_o2,
                       const float* __restrict__ W_s2, const float* __restrict__ b_s2,
                       const float* __restrict__ ag1, const float* __restrict__ ag2,
                       float* __restrict__ Mo, float* __restrict__ Ms,
                       float* __restrict__ beta, float* __restrict__ cc) {
    __shared__ float vsh[128];
    int t = threadIdx.x;  // 128 threads
    float s = 0.f;
    for (int j = 0; j < 64; ++j) s += dec1_W[t * 64 + j] * dec2_W[j];
    vsh[t] = s;
    __syncthreads();
    const float* vlo = vsh;
    const float* vhi = vsh + 64;
    float m0 = 0, m1 = 0, m2 = 0, n0 = 0, n1 = 0, n2 = 0;
    for (int k = 0; k < 64; ++k) {
        float wo = W_o2[t * 64 + k], wsv = W_s2[t * 64 + k];
        m0 += wo * ag1[k];  m1 += wo * vlo[k];  m2 += wo * vhi[k];
        n0 += wsv * ag2[k]; n1 += wsv * vlo[k]; n2 += wsv * vhi[k];
    }
    Mo[0 * 128 + t] = m0; Mo[1 * 128 + t] = m1; Mo[2 * 128 + t] = m2;
    Ms[0 * 128 + t] = n0; Ms[1 * 128 + t] = n1; Ms[2 * 128 + t] = n2;
    if (t == 0) {
        float b0 = 0, b1 = 0, b2 = 0, s0 = 0, s1 = 0, s2 = 0, c0 = 0;
        for (int k = 0; k < 64; ++k) {
            b0 += b_o2[k] * ag1[k]; b1 += b_o2[k] * vlo[k]; b2 += b_o2[k] * vhi[k];
            s0 += b_s2[k] * ag2[k]; s1 += b_s2[k] * vlo[k]; s2 += b_s2[k] * vhi[k];
            c0 += dec1_b[k] * dec2_W[k];
        }
        beta[0] = b0; beta[1] = b1; beta[2] = b2;
        beta[4] = s0; beta[5] = s1; beta[6] = s2;
        *cc = c0 + dec2_b[0];
    }
}

// ---------------- tiled f32 GEMM -> bf16 output, both branches ----------------
__global__ __launch_bounds__(256) void gemm2_k(const float* __restrict__ X,
                                               const float* __restrict__ W0,
                                               const float* __restrict__ W1,
                                               unsigned short* __restrict__ S0,
                                               unsigned short* __restrict__ S1,
                                               int nrows) {
    __shared__ __align__(16) float XL[128 * 17];
    __shared__ __align__(16) float WL[16 * 132];

    const float* W = (blockIdx.y == 0) ? W0 : W1;
    unsigned short* S = (blockIdx.y == 0) ? S0 : S1;

    const int tid = threadIdx.x;
    const int tx = tid & 15;
    const int ty = tid >> 4;
    const int row0 = blockIdx.x * 128;
    const int c0 = tx * 8;
    const int r0 = ty * 8;

    float acc[8][8];
#pragma unroll
    for (int i = 0; i < 8; ++i)
#pragma unroll
        for (int j = 0; j < 8; ++j) acc[i][j] = 0.f;

    const float4* X4 = (const float4*)X;
    const float4* W4 = (const float4*)W;

    for (int kp = 0; kp < 8; ++kp) {
        if (kp) __syncthreads();
#pragma unroll
        for (int it = 0; it < 2; ++it) {
            int f = it * 256 + tid;
            int r = f >> 2, kq = f & 3;
            int gr = row0 + r;
            if (gr >= nrows) gr = nrows - 1;
            float4 v = X4[(size_t)gr * 32 + kp * 4 + kq];
            int base = r * 17 + kq * 4;
            XL[base + 0] = v.x; XL[base + 1] = v.y;
            XL[base + 2] = v.z; XL[base + 3] = v.w;
        }
#pragma unroll
        for (int it = 0; it < 2; ++it) {
            int f = it * 256 + tid;
            int kk = f >> 5, cq = f & 31;
            float4 v = W4[(size_t)(kp * 16 + kk) * 32 + cq];
            *(float4*)&WL[kk * 132 + cq * 4] = v;
        }
        __syncthreads();

#pragma unroll 4
        for (int kk = 0; kk < 16; ++kk) {
            float xr[8];
#pragma unroll
            for (int i = 0; i < 8; ++i) xr[i] = XL[(r0 + i) * 17 + kk];
            float4 wa = *(const float4*)&WL[kk * 132 + c0];
            float4 wb = *(const float4*)&WL[kk * 132 + c0 + 4];
            float wv[8] = {wa.x, wa.y, wa.z, wa.w, wb.x, wb.y, wb.z, wb.w};
#pragma unroll
            for (int i = 0; i < 8; ++i)
#pragma unroll
                for (int j = 0; j < 8; ++j) acc[i][j] += xr[i] * wv[j];
        }
    }

#pragma unroll
    for (int i = 0; i < 8; ++i) {
        int gr = row0 + r0 + i;
        if (gr < nrows) {
            union { unsigned short h[8]; uint4 u4; } p;
#pragma unroll
            for (int j = 0; j < 8; ++j) p.h[j] = f2bf(acc[i][j]);
            ((uint4*)S)[(size_t)gr * 16 + tx] = p.u4;
        }
    }
}

// ------- layer-1 gather SpMM (bf16 rows) + bias + relu + 3-way projection ----
__global__ __launch_bounds__(256) void seg_spmm_fused2_k(
    const int* __restrict__ rp2, const int2* __restrict__ csr,
    const unsigned short* __restrict__ So, const unsigned short* __restrict__ Ss,
    const float* __restrict__ bias_o, const float* __restrict__ bias_s,
    const float* __restrict__ Mo, const float* __restrict__ Ms,
    float4* __restrict__ To, float4* __restrict__ Ts, int n) {
    const int* rp;
    const unsigned int* S;
    const float* bias;
    const float* M;
    float4* T;
    if (blockIdx.y == 0) {
        rp = rp2;     S = (const unsigned int*)So; bias = bias_o; M = Mo; T = To;
    } else {
        rp = rp2 + n; S = (const unsigned int*)Ss; bias = bias_s; M = Ms; T = Ts;
    }
    int wid = (blockIdx.x * 256 + threadIdx.x) >> 6;
    int lane = threadIdx.x & 63;
    if (wid >= n) return;
    int e = rp[wid], end = rp[wid + 1];
    float ax = 0.f, ay = 0.f;
    for (; e + 7 < end; e += 8) {
        int2 c0 = csr[e],     c1 = csr[e + 1], c2 = csr[e + 2], c3 = csr[e + 3];
        int2 c4 = csr[e + 4], c5 = csr[e + 5], c6 = csr[e + 6], c7 = csr[e + 7];
        float2 m0 = bf2f2(S[c0.x * 64 + lane]);
        float2 m1 = bf2f2(S[c1.x * 64 + lane]);
        float2 m2 = bf2f2(S[c2.x * 64 + lane]);
        float2 m3 = bf2f2(S[c3.x * 64 + lane]);
        float2 m4 = bf2f2(S[c4.x * 64 + lane]);
        float2 m5 = bf2f2(S[c5.x * 64 + lane]);
        float2 m6 = bf2f2(S[c6.x * 64 + lane]);
        float2 m7 = bf2f2(S[c7.x * 64 + lane]);
        float v0 = __int_as_float(c0.y), v1 = __int_as_float(c1.y);
        float v2 = __int_as_float(c2.y), v3 = __int_as_float(c3.y);
        float v4 = __int_as_float(c4.y), v5 = __int_as_float(c5.y);
        float v6 = __int_as_float(c6.y), v7 = __int_as_float(c7.y);
        ax += m0.x * v0 + m1.x * v1 + m2.x * v2 + m3.x * v3;
        ay += m0.y * v0 + m1.y * v1 + m2.y * v2 + m3.y * v3;
        ax += m4.x * v4 + m5.x * v5 + m6.x * v6 + m7.x * v7;
        ay += m4.y * v4 + m5.y * v5 + m6.y * v6 + m7.y * v7;
    }
    for (; e + 3 < end; e += 4) {
        int2 c0 = csr[e], c1 = csr[e + 1], c2 = csr[e + 2], c3 = csr[e + 3];
        float2 m0 = bf2f2(S[c0.x * 64 + lane]);
        float2 m1 = bf2f2(S[c1.x * 64 + lane]);
        float2 m2 = bf2f2(S[c2.x * 64 + lane]);
        float2 m3 = bf2f2(S[c3.x * 64 + lane]);
        float v0 = __int_as_float(c0.y), v1 = __int_as_float(c1.y);
        float v2 = __int_as_float(c2.y), v3 = __int_as_float(c3.y);
        ax += m0.x * v0 + m1.x * v1 + m2.x * v2 + m3.x * v3;
        ay += m0.y * v0 + m1.y * v1 + m2.y * v2 + m3.y * v3;
    }
    for (; e < end; ++e) {
        int2 c = csr[e];
        float2 m = bf2f2(S[c.x * 64 + lane]);
        float v = __int_as_float(c.y);
        ax += m.x * v;
        ay += m.y * v;
    }
    float2 bb = ((const float2*)bias)[lane];
    ax = fmaxf(ax + bb.x, 0.f);
    ay = fmaxf(ay + bb.y, 0.f);
    float2 M0 = ((const float2*)(M + 0 * 128))[lane];
    float2 M1 = ((const float2*)(M + 1 * 128))[lane];
    float2 M2 = ((const float2*)(M + 2 * 128))[lane];
    float d = wave_sum64(ax * M0.x + ay * M0.y);
    float u = wave_sum64(ax * M1.x + ay * M1.y);
    float w = wave_sum64(ax * M2.x + ay * M2.y);
    if (lane == 0) T[wid] = make_float4(d, u, w, 0.f);
}

// ------- layer-2 scalar SpMM (both graphs) + gate + decode projections -------
__global__ __launch_bounds__(256) void gate_k(
    const int* __restrict__ rp2, const int2* __restrict__ csr,
    const float4* __restrict__ To, const float4* __restrict__ Ts,
    const float* __restrict__ beta,
    float* __restrict__ a, float* __restrict__ b, int n) {
    int i = blockIdx.x * 256 + threadIdx.x;
    if (i >= n) return;
    float d1 = 0.f, u1 = 0.f, w1 = 0.f;
    {
        int e = rp2[i], end = rp2[i + 1];
        for (; e + 3 < end; e += 4) {
            int2 c0 = csr[e], c1 = csr[e + 1], c2 = csr[e + 2], c3 = csr[e + 3];
            float4 t0 = To[c0.x];
            float4 t1 = To[c1.x];
            float4 t2 = To[c2.x];
            float4 t3 = To[c3.x];
            float v0 = __int_as_float(c0.y), v1 = __int_as_float(c1.y);
            float v2 = __int_as_float(c2.y), v3 = __int_as_float(c3.y);
            d1 += t0.x * v0 + t1.x * v1 + t2.x * v2 + t3.x * v3;
            u1 += t0.y * v0 + t1.y * v1 + t2.y * v2 + t3.y * v3;
            w1 += t0.z * v0 + t1.z * v1 + t2.z * v2 + t3.z * v3;
        }
        for (; e < end; ++e) {
            int2 c = csr[e];
            float4 t = To[c.x];
            float v = __int_as_float(c.y);
            d1 += t.x * v; u1 += t.y * v; w1 += t.z * v;
        }
    }
    float d2 = 0.f, u2 = 0.f, w2 = 0.f;
    {
        int e = rp2[n + i], end = rp2[n + i + 1];
        for (; e + 3 < end; e += 4) {
            int2 c0 = csr[e], c1 = csr[e + 1], c2 = csr[e + 2], c3 = csr[e + 3];
            float4 t0 = Ts[c0.x];
            float4 t1 = Ts[c1.x];
            float4 t2 = Ts[c2.x];
            float4 t3 = Ts[c3.x];
            float v0 = __int_as_float(c0.y), v1 = __int_as_float(c1.y);
            float v2 = __int_as_float(c2.y), v3 = __int_as_float(c3.y);
            d2 += t0.x * v0 + t1.x * v1 + t2.x * v2 + t3.x * v3;
            u2 += t0.y * v0 + t1.y * v1 + t2.y * v2 + t3.y * v3;
            w2 += t0.z * v0 + t1.z * v1 + t2.z * v2 + t3.z * v3;
        }
        for (; e < end; ++e) {
            int2 c = csr[e];
            float4 t = Ts[c.x];
            float v = __int_as_float(c.y);
            d2 += t.x * v; u2 += t.y * v; w2 += t.z * v;
        }
    }
    d1 += beta[0]; u1 += beta[1]; w1 += beta[2];
    d2 += beta[4]; u2 += beta[5]; w2 += beta[6];
    a[i] = d1 * u1 + d2 * u2;
    b[i] = d1 * w1 + d2 * w2;
}

__global__ __launch_bounds__(256) void decode_k(const int* __restrict__ idx,
                                                const float* __restrict__ a,
                                                const float* __restrict__ b,
                                                const float* __restrict__ c,
                                                float* __restrict__ out, int P) {
    int i = blockIdx.x * 256 + threadIdx.x;
    if (i >= P) return;
    out[i] = a[idx[i]] + b[idx[P + i]] + *c;
}

// ---------------------------------------------------------------------------

extern "C" void kernel_launch(void* const* d_in, const int* in_sizes, int n_in,
                              void* d_out, int out_size, void* d_ws, size_t ws_size,
                              hipStream_t stream) {
    const float* x      = (const float*)d_in[0];
    const int*   o_edges= (const int*)d_in[1];
    const float* o_vals = (const float*)d_in[2];
    const int*   s_edges= (const int*)d_in[3];
    const float* s_vals = (const float*)d_in[4];
    const int*   idx    = (const int*)d_in[5];
    const float* W_o1   = (const float*)d_in[6];
    const float* b_o1   = (const float*)d_in[7];
    const float* W_o2   = (const float*)d_in[8];
    const float* b_o2   = (const float*)d_in[9];
    const float* W_s1   = (const float*)d_in[10];
    const float* b_s1   = (const float*)d_in[11];
    const float* W_s2   = (const float*)d_in[12];
    const float* b_s2   = (const float*)d_in[13];
    const float* ag1    = (const float*)d_in[14];
    const float* ag2    = (const float*)d_in[15];
    const float* dec1_W = (const float*)d_in[16];
    const float* dec1_b = (const float*)d_in[17];
    const float* dec2_W = (const float*)d_in[18];
    const float* dec2_b = (const float*)d_in[19];
    float* out = (float*)d_out;

    const int N = in_sizes[0] / 128;
    const int E = in_sizes[1] / 2;
    const int P = out_size;
    const int n2 = 2 * N;
    const int nb = (n2 + BKT_NODES - 1) / BKT_NODES;  // 782 for N=100k

    const size_t NBH = (size_t)N * 128 * 2;  // [N,128] bf16 bytes

    char* ws = (char*)d_ws;
    size_t off = 0;
    auto alloc = [&](size_t bytes) {
        char* p = ws + off;
        off += (bytes + 255) & ~(size_t)255;
        return p;
    };

    unsigned short* B0 = (unsigned short*)alloc(NBH);  // S1o (bf16)
    unsigned short* B1 = (unsigned short*)alloc(NBH);  // S1s (bf16)
    float4* To = (float4*)alloc((size_t)N * 16);
    float4* Ts = (float4*)alloc((size_t)N * 16);
    float* av = (float*)alloc((size_t)P * 4);
    float* bv = (float*)alloc((size_t)P * 4);
    float* Mo = (float*)alloc(3 * 128 * 4);
    float* Ms = (float*)alloc(3 * 128 * 4);
    float* beta = (float*)alloc(32);
    float* cc = (float*)alloc(16);
    int* bcnt  = (int*)alloc((size_t)nb * 4);
    int* bbase = (int*)alloc((size_t)(nb + 1) * 4);
    int* bcur  = (int*)alloc((size_t)nb * 4);
    int* rp2   = (int*)alloc((size_t)(n2 + 1) * 4);
    int2* binned = (int2*)alloc((size_t)2 * E * 8);
    int2* csr    = (int2*)alloc((size_t)2 * E * 8);

    const int nblk = (N + 255) / 256;

    // ---- CSR build: two-level bucket sort ----
    hipMemsetAsync(bcnt, 0, (size_t)nb * 4, stream);
    bhist_k<<<512, 256, 0, stream>>>(o_edges, s_edges, bcnt, E, N, nb);
    bscan_k<<<1, 1024, 0, stream>>>(bcnt, bbase, bcur, nb, 2 * E);
    const int chunk = 8192;
    bin_k<<<(2 * E + chunk - 1) / chunk, 256, 0, stream>>>(
        o_edges, o_vals, s_edges, s_vals, bcur, binned, E, N, nb, chunk);
    sort_k<<<nb, 256, 0, stream>>>(bbase, binned, csr, rp2, n2, 2 * E);

    // ---- projection precompute ----
    prep_k<<<1, 128, 0, stream>>>(dec1_W, dec1_b, dec2_W, dec2_b,
                                  W_o2, b_o2, W_s2, b_s2, ag1, ag2,
                                  Mo, Ms, beta, cc);

    // ---- layer 1 GEMMs (both branches, bf16 output) ----
    dim3 ggrid((N + 127) / 128, 2);
    gemm2_k<<<ggrid, 256, 0, stream>>>(x, W_o1, W_s1, B0, B1, N);

    // ---- layer-1 SpMM + bias + relu + projection to 3 scalars (both) ----
    dim3 sgrid((N * 64 + 255) / 256, 2);
    seg_spmm_fused2_k<<<sgrid, 256, 0, stream>>>(rp2, csr, B0, B1, b_o1, b_s1,
                                                 Mo, Ms, To, Ts, N);

    // ---- layer-2 scalar SpMM + gate ----
    gate_k<<<nblk, 256, 0, stream>>>(rp2, csr, To, Ts, beta, av, bv, N);

    decode_k<<<(P + 255) / 256, 256, 0, stream>>>(idx, av, bv, cc, out, P);
}

// Round 10
// 314.644 us; speedup vs baseline: 27.4105x; 1.1707x over previous
//
#include <hip/hip_runtime.h>

// ---------------------------------------------------------------------------
// IGCN link prediction, round 9.
// - Layer-2 collapsed to scalars (R4), bf16 S1 (R6), packed CSR (R7),
//   two-level bucket-sort CSR build (R8).
// - NEW: layer-1 GEMM uses bf16 MFMA (v_mfma_f32_16x16x32_bf16).
//   X and W^T staged in LDS as bf16 with XOR-swizzled 16B blocks
//   (blk' = blk ^ (row&15)) -> conflict-optimal ds_read_b128 frags,
//   no padding, exactly 64KB LDS. f32 VALU GEMM had a 42us compute floor;
//   MFMA version is memory-bound (~25-40us).
// ---------------------------------------------------------------------------

constexpr int BKT_SHIFT = 8;     // 256 nodes per bucket
constexpr int BKT_NODES = 256;
constexpr int SORT_CAP  = 7168;  // records/bucket LDS capacity

typedef __attribute__((ext_vector_type(8))) short bf16x8;
typedef __attribute__((ext_vector_type(4))) float f32x4;

__device__ __forceinline__ float wave_sum64(float x) {
#pragma unroll
    for (int o = 32; o > 0; o >>= 1) x += __shfl_xor(x, o, 64);
    return x;
}

__device__ __forceinline__ unsigned short f2bf(float f) {  // round-nearest-even
    unsigned int u = __float_as_uint(f);
    u += 0x7FFF + ((u >> 16) & 1);
    return (unsigned short)(u >> 16);
}

__device__ __forceinline__ float2 bf2f2(unsigned int u) {  // 2 bf16 -> 2 f32
    float2 r;
    r.x = __uint_as_float(u << 16);
    r.y = __uint_as_float(u & 0xFFFF0000u);
    return r;
}

// ---------------- two-level bucket CSR build ----------------

__global__ __launch_bounds__(256) void bhist_k(const int* __restrict__ eo,
                                               const int* __restrict__ es,
                                               int* __restrict__ bcnt,
                                               int E, int N, int nb) {
    __shared__ int lh[1024];
    for (int i = threadIdx.x; i < nb; i += 256) lh[i] = 0;
    __syncthreads();
    int total = 2 * E;
    for (int t = blockIdx.x * 256 + threadIdx.x; t < total; t += gridDim.x * 256) {
        int g = (t >= E) ? 1 : 0;
        int e = g ? t - E : t;
        int dst = (g ? es : eo)[e];
        atomicAdd(&lh[(g * N + dst) >> BKT_SHIFT], 1);
    }
    __syncthreads();
    for (int i = threadIdx.x; i < nb; i += 256) {
        int v = lh[i];
        if (v) atomicAdd(&bcnt[i], v);
    }
}

__global__ __launch_bounds__(1024) void bscan_k(const int* __restrict__ bcnt,
                                                int* __restrict__ bbase,
                                                int* __restrict__ bcur,
                                                int nb, int total) {
    __shared__ int sh[1024];
    int t = threadIdx.x;
    int v = (t < nb) ? bcnt[t] : 0;
    sh[t] = v;
    __syncthreads();
#pragma unroll
    for (int o = 1; o < 1024; o <<= 1) {
        int tv = (t >= o) ? sh[t - o] : 0;
        __syncthreads();
        sh[t] += tv;
        __syncthreads();
    }
    if (t < nb) {
        int b = sh[t] - v;
        bbase[t] = b;
        bcur[t] = b;
    }
    if (t == 0) bbase[nb] = total;
}

__global__ __launch_bounds__(256) void bin_k(const int* __restrict__ eo,
                                             const float* __restrict__ vo,
                                             const int* __restrict__ es,
                                             const float* __restrict__ vs,
                                             int* __restrict__ bcur,
                                             int2* __restrict__ binned,
                                             int E, int N, int nb, int chunk) {
    __shared__ int lcnt[1024];
    __shared__ int lbase[1024];
    int c0 = blockIdx.x * chunk;
    int c1 = min(c0 + chunk, 2 * E);
    for (int i = threadIdx.x; i < nb; i += 256) lcnt[i] = 0;
    __syncthreads();
    for (int t = c0 + threadIdx.x; t < c1; t += 256) {
        int g = (t >= E) ? 1 : 0;
        int e = g ? t - E : t;
        int dst = (g ? es : eo)[e];
        atomicAdd(&lcnt[(g * N + dst) >> BKT_SHIFT], 1);
    }
    __syncthreads();
    for (int i = threadIdx.x; i < nb; i += 256) {
        int v = lcnt[i];
        lbase[i] = v ? atomicAdd(&bcur[i], v) : 0;
        lcnt[i] = 0;  // reuse as local cursor
    }
    __syncthreads();
    for (int t = c0 + threadIdx.x; t < c1; t += 256) {
        int g = (t >= E) ? 1 : 0;
        int e = g ? t - E : t;
        const int* edges = g ? es : eo;
        int dst = edges[e];
        int dc = g * N + dst;
        int b = dc >> BKT_SHIFT;
        int pos = lbase[b] + atomicAdd(&lcnt[b], 1);
        int src = edges[E + e];
        float val = (g ? vs : vo)[e];
        binned[pos] = make_int2(((dc & (BKT_NODES - 1)) << 17) | src,
                                __float_as_int(val));
    }
}

__global__ __launch_bounds__(256) void sort_k(const int* __restrict__ bbase,
                                              const int2* __restrict__ binned,
                                              int2* __restrict__ csr,
                                              int* __restrict__ rp2,
                                              int n2, int total) {
    __shared__ int2 lrec[SORT_CAP];
    __shared__ int ldeg[BKT_NODES];
    __shared__ int lsc[BKT_NODES];
    int b = blockIdx.x;
    int base = bbase[b];
    int count = min(bbase[b + 1] - base, SORT_CAP);
    int tid = threadIdx.x;
    for (int k = tid; k < count; k += 256) lrec[k] = binned[base + k];
    ldeg[tid] = 0;
    __syncthreads();
    for (int k = tid; k < count; k += 256) atomicAdd(&ldeg[lrec[k].x >> 17], 1);
    __syncthreads();
    int v = ldeg[tid];
    lsc[tid] = v;
    __syncthreads();
#pragma unroll
    for (int o = 1; o < 256; o <<= 1) {
        int tv = (tid >= o) ? lsc[tid - o] : 0;
        __syncthreads();
        lsc[tid] += tv;
        __syncthreads();
    }
    int excl = lsc[tid] - v;
    int node = b * BKT_NODES + tid;
    if (node < n2) rp2[node] = base + excl;
    if (b == 0 && tid == 0) rp2[n2] = total;
    ldeg[tid] = excl;  // reuse as scatter cursor
    __syncthreads();
    for (int k = tid; k < count; k += 256) {
        int2 r = lrec[k];
        int dl = r.x >> 17;
        int p = atomicAdd(&ldeg[dl], 1);
        csr[base + p] = make_int2(r.x & 0x1FFFF, r.y);
    }
}

// ---------------- precompute projections ----------------
__global__ void prep_k(const float* __restrict__ dec1_W, const float* __restrict__ dec1_b,
                       const float* __restrict__ dec2_W, const float* __restrict__ dec2_b,
                       const float* __restrict__ W_o2, const float* __restrict__ b_o2,
                       const float* __restrict__ W_s2, const float* __restrict__ b_s2,
                       const float* __restrict__ ag1, const float* __restrict__ ag2,
                       float* __restrict__ Mo, float* __restrict__ Ms,
                       float* __restrict__ beta, float* __restrict__ cc) {
    __shared__ float vsh[128];
    int t = threadIdx.x;  // 128 threads
    float s = 0.f;
    for (int j = 0; j < 64; ++j) s += dec1_W[t * 64 + j] * dec2_W[j];
    vsh[t] = s;
    __syncthreads();
    const float* vlo = vsh;
    const float* vhi = vsh + 64;
    float m0 = 0, m1 = 0, m2 = 0, n0 = 0, n1 = 0, n2 = 0;
    for (int k = 0; k < 64; ++k) {
        float wo = W_o2[t * 64 + k], wsv = W_s2[t * 64 + k];
        m0 += wo * ag1[k];  m1 += wo * vlo[k];  m2 += wo * vhi[k];
        n0 += wsv * ag2[k]; n1 += wsv * vlo[k]; n2 += wsv * vhi[k];
    }
    Mo[0 * 128 + t] = m0; Mo[1 * 128 + t] = m1; Mo[2 * 128 + t] = m2;
    Ms[0 * 128 + t] = n0; Ms[1 * 128 + t] = n1; Ms[2 * 128 + t] = n2;
    if (t == 0) {
        float b0 = 0, b1 = 0, b2 = 0, s0 = 0, s1 = 0, s2 = 0, c0 = 0;
        for (int k = 0; k < 64; ++k) {
            b0 += b_o2[k] * ag1[k]; b1 += b_o2[k] * vlo[k]; b2 += b_o2[k] * vhi[k];
            s0 += b_s2[k] * ag2[k]; s1 += b_s2[k] * vlo[k]; s2 += b_s2[k] * vhi[k];
            c0 += dec1_b[k] * dec2_W[k];
        }
        beta[0] = b0; beta[1] = b1; beta[2] = b2;
        beta[4] = s0; beta[5] = s1; beta[6] = s2;
        *cc = c0 + dec2_b[0];
    }
}

// ---------------- bf16 MFMA GEMM: S[b][n,128](bf16) = X @ W[b] ----------------
// 128-row tile per block, full K=128 staged. XL[r][k], WT[c][k] bf16 in LDS,
// 16B blocks XOR-swizzled by (row&15). 4 waves x (2 rowtiles x 8 coltiles).
__global__ __launch_bounds__(256) void gemm_mfma_k(const float* __restrict__ X,
                                                   const float* __restrict__ W0,
                                                   const float* __restrict__ W1,
                                                   unsigned short* __restrict__ S0,
                                                   unsigned short* __restrict__ S1,
                                                   int nrows) {
    __shared__ unsigned short XL[128 * 128];  // 32 KB
    __shared__ unsigned short WT[128 * 128];  // 32 KB

    const float* W = blockIdx.y ? W1 : W0;
    unsigned short* S = blockIdx.y ? S1 : S0;

    const int tid = threadIdx.x;
    const int row0 = blockIdx.x * 128;
    const float4* X4 = (const float4*)X;

    // stage X tile -> XL (bf16, swizzled blocks)
#pragma unroll
    for (int i = 0; i < 16; ++i) {
        int f = i * 256 + tid;
        int r = f >> 5, q = f & 31;        // row, float4-quad (4 cols)
        int gr = row0 + r;
        if (gr >= nrows) gr = nrows - 1;   // clamp; stores guarded
        float4 v = X4[(size_t)gr * 32 + q];
        unsigned int w0 = (unsigned int)f2bf(v.x) | ((unsigned int)f2bf(v.y) << 16);
        unsigned int w1 = (unsigned int)f2bf(v.z) | ((unsigned int)f2bf(v.w) << 16);
        int bp = (q >> 1) ^ (r & 15);      // swizzled 16B-block index
        unsigned int* p = (unsigned int*)&XL[r * 128 + bp * 8 + (q & 1) * 4];
        p[0] = w0;
        p[1] = w1;
    }
    // stage W transposed -> WT (bf16, swizzled blocks). thread pair owns a col.
    {
        int c = tid >> 1;
        int kh = (tid & 1) * 64;
#pragma unroll 8
        for (int k2 = 0; k2 < 32; ++k2) {
            int k = kh + 2 * k2;
            unsigned int lo = f2bf(W[k * 128 + c]);
            unsigned int hi = f2bf(W[(k + 1) * 128 + c]);
            int bp = (k >> 3) ^ (c & 15);
            ((unsigned int*)&WT[c * 128 + bp * 8])[(k >> 1) & 3] = lo | (hi << 16);
        }
    }
    __syncthreads();

    const int w4 = (tid >> 6) * 32;   // wave's row base in tile
    const int lr = tid & 15;          // A-row / B-col / D-col lane index
    const int kg = (tid >> 4) & 3;    // k-group

    bf16x8 a[2][4];
#pragma unroll
    for (int rt = 0; rt < 2; ++rt)
#pragma unroll
        for (int kt = 0; kt < 4; ++kt)
            a[rt][kt] = *(const bf16x8*)&XL[(w4 + rt * 16 + lr) * 128 +
                                            (((kt * 4 + kg) ^ lr) * 8)];

    f32x4 acc[2][8];
#pragma unroll
    for (int rt = 0; rt < 2; ++rt)
#pragma unroll
        for (int ct = 0; ct < 8; ++ct) acc[rt][ct] = (f32x4){0.f, 0.f, 0.f, 0.f};

#pragma unroll
    for (int ct = 0; ct < 8; ++ct) {
#pragma unroll
        for (int kt = 0; kt < 4; ++kt) {
            bf16x8 b = *(const bf16x8*)&WT[(ct * 16 + lr) * 128 +
                                           (((kt * 4 + kg) ^ lr) * 8)];
            acc[0][ct] = __builtin_amdgcn_mfma_f32_16x16x32_bf16(a[0][kt], b, acc[0][ct], 0, 0, 0);
            acc[1][ct] = __builtin_amdgcn_mfma_f32_16x16x32_bf16(a[1][kt], b, acc[1][ct], 0, 0, 0);
        }
    }

    // D: col = lane&15, row = (lane>>4)*4 + reg
#pragma unroll
    for (int rt = 0; rt < 2; ++rt)
#pragma unroll
        for (int j = 0; j < 4; ++j) {
            int gr = row0 + w4 + rt * 16 + kg * 4 + j;
            if (gr < nrows) {
                size_t rb = (size_t)gr * 128 + lr;
#pragma unroll
                for (int ct = 0; ct < 8; ++ct)
                    S[rb + ct * 16] = f2bf(acc[rt][ct][j]);
            }
        }
}

// ------- layer-1 gather SpMM (bf16 rows) + bias + relu + 3-way projection ----
__global__ __launch_bounds__(256) void seg_spmm_fused2_k(
    const int* __restrict__ rp2, const int2* __restrict__ csr,
    const unsigned short* __restrict__ So, const unsigned short* __restrict__ Ss,
    const float* __restrict__ bias_o, const float* __restrict__ bias_s,
    const float* __restrict__ Mo, const float* __restrict__ Ms,
    float4* __restrict__ To, float4* __restrict__ Ts, int n) {
    const int* rp;
    const unsigned int* S;
    const float* bias;
    const float* M;
    float4* T;
    if (blockIdx.y == 0) {
        rp = rp2;     S = (const unsigned int*)So; bias = bias_o; M = Mo; T = To;
    } else {
        rp = rp2 + n; S = (const unsigned int*)Ss; bias = bias_s; M = Ms; T = Ts;
    }
    int wid = (blockIdx.x * 256 + threadIdx.x) >> 6;
    int lane = threadIdx.x & 63;
    if (wid >= n) return;
    int e = rp[wid], end = rp[wid + 1];
    float ax = 0.f, ay = 0.f;
    for (; e + 7 < end; e += 8) {
        int2 c0 = csr[e],     c1 = csr[e + 1], c2 = csr[e + 2], c3 = csr[e + 3];
        int2 c4 = csr[e + 4], c5 = csr[e + 5], c6 = csr[e + 6], c7 = csr[e + 7];
        float2 m0 = bf2f2(S[c0.x * 64 + lane]);
        float2 m1 = bf2f2(S[c1.x * 64 + lane]);
        float2 m2 = bf2f2(S[c2.x * 64 + lane]);
        float2 m3 = bf2f2(S[c3.x * 64 + lane]);
        float2 m4 = bf2f2(S[c4.x * 64 + lane]);
        float2 m5 = bf2f2(S[c5.x * 64 + lane]);
        float2 m6 = bf2f2(S[c6.x * 64 + lane]);
        float2 m7 = bf2f2(S[c7.x * 64 + lane]);
        float v0 = __int_as_float(c0.y), v1 = __int_as_float(c1.y);
        float v2 = __int_as_float(c2.y), v3 = __int_as_float(c3.y);
        float v4 = __int_as_float(c4.y), v5 = __int_as_float(c5.y);
        float v6 = __int_as_float(c6.y), v7 = __int_as_float(c7.y);
        ax += m0.x * v0 + m1.x * v1 + m2.x * v2 + m3.x * v3;
        ay += m0.y * v0 + m1.y * v1 + m2.y * v2 + m3.y * v3;
        ax += m4.x * v4 + m5.x * v5 + m6.x * v6 + m7.x * v7;
        ay += m4.y * v4 + m5.y * v5 + m6.y * v6 + m7.y * v7;
    }
    for (; e + 3 < end; e += 4) {
        int2 c0 = csr[e], c1 = csr[e + 1], c2 = csr[e + 2], c3 = csr[e + 3];
        float2 m0 = bf2f2(S[c0.x * 64 + lane]);
        float2 m1 = bf2f2(S[c1.x * 64 + lane]);
        float2 m2 = bf2f2(S[c2.x * 64 + lane]);
        float2 m3 = bf2f2(S[c3.x * 64 + lane]);
        float v0 = __int_as_float(c0.y), v1 = __int_as_float(c1.y);
        float v2 = __int_as_float(c2.y), v3 = __int_as_float(c3.y);
        ax += m0.x * v0 + m1.x * v1 + m2.x * v2 + m3.x * v3;
        ay += m0.y * v0 + m1.y * v1 + m2.y * v2 + m3.y * v3;
    }
    for (; e < end; ++e) {
        int2 c = csr[e];
        float2 m = bf2f2(S[c.x * 64 + lane]);
        float v = __int_as_float(c.y);
        ax += m.x * v;
        ay += m.y * v;
    }
    float2 bb = ((const float2*)bias)[lane];
    ax = fmaxf(ax + bb.x, 0.f);
    ay = fmaxf(ay + bb.y, 0.f);
    float2 M0 = ((const float2*)(M + 0 * 128))[lane];
    float2 M1 = ((const float2*)(M + 1 * 128))[lane];
    float2 M2 = ((const float2*)(M + 2 * 128))[lane];
    float d = wave_sum64(ax * M0.x + ay * M0.y);
    float u = wave_sum64(ax * M1.x + ay * M1.y);
    float w = wave_sum64(ax * M2.x + ay * M2.y);
    if (lane == 0) T[wid] = make_float4(d, u, w, 0.f);
}

// ------- layer-2 scalar SpMM (both graphs) + gate + decode projections -------
__global__ __launch_bounds__(256) void gate_k(
    const int* __restrict__ rp2, const int2* __restrict__ csr,
    const float4* __restrict__ To, const float4* __restrict__ Ts,
    const float* __restrict__ beta,
    float* __restrict__ a, float* __restrict__ b, int n) {
    int i = blockIdx.x * 256 + threadIdx.x;
    if (i >= n) return;
    float d1 = 0.f, u1 = 0.f, w1 = 0.f;
    {
        int e = rp2[i], end = rp2[i + 1];
        for (; e + 3 < end; e += 4) {
            int2 c0 = csr[e], c1 = csr[e + 1], c2 = csr[e + 2], c3 = csr[e + 3];
            float4 t0 = To[c0.x];
            float4 t1 = To[c1.x];
            float4 t2 = To[c2.x];
            float4 t3 = To[c3.x];
            float v0 = __int_as_float(c0.y), v1 = __int_as_float(c1.y);
            float v2 = __int_as_float(c2.y), v3 = __int_as_float(c3.y);
            d1 += t0.x * v0 + t1.x * v1 + t2.x * v2 + t3.x * v3;
            u1 += t0.y * v0 + t1.y * v1 + t2.y * v2 + t3.y * v3;
            w1 += t0.z * v0 + t1.z * v1 + t2.z * v2 + t3.z * v3;
        }
        for (; e < end; ++e) {
            int2 c = csr[e];
            float4 t = To[c.x];
            float v = __int_as_float(c.y);
            d1 += t.x * v; u1 += t.y * v; w1 += t.z * v;
        }
    }
    float d2 = 0.f, u2 = 0.f, w2 = 0.f;
    {
        int e = rp2[n + i], end = rp2[n + i + 1];
        for (; e + 3 < end; e += 4) {
            int2 c0 = csr[e], c1 = csr[e + 1], c2 = csr[e + 2], c3 = csr[e + 3];
            float4 t0 = Ts[c0.x];
            float4 t1 = Ts[c1.x];
            float4 t2 = Ts[c2.x];
            float4 t3 = Ts[c3.x];
            float v0 = __int_as_float(c0.y), v1 = __int_as_float(c1.y);
            float v2 = __int_as_float(c2.y), v3 = __int_as_float(c3.y);
            d2 += t0.x * v0 + t1.x * v1 + t2.x * v2 + t3.x * v3;
            u2 += t0.y * v0 + t1.y * v1 + t2.y * v2 + t3.y * v3;
            w2 += t0.z * v0 + t1.z * v1 + t2.z * v2 + t3.z * v3;
        }
        for (; e < end; ++e) {
            int2 c = csr[e];
            float4 t = Ts[c.x];
            float v = __int_as_float(c.y);
            d2 += t.x * v; u2 += t.y * v; w2 += t.z * v;
        }
    }
    d1 += beta[0]; u1 += beta[1]; w1 += beta[2];
    d2 += beta[4]; u2 += beta[5]; w2 += beta[6];
    a[i] = d1 * u1 + d2 * u2;
    b[i] = d1 * w1 + d2 * w2;
}

__global__ __launch_bounds__(256) void decode_k(const int* __restrict__ idx,
                                                const float* __restrict__ a,
                                                const float* __restrict__ b,
                                                const float* __restrict__ c,
                                                float* __restrict__ out, int P) {
    int i = blockIdx.x * 256 + threadIdx.x;
    if (i >= P) return;
    out[i] = a[idx[i]] + b[idx[P + i]] + *c;
}

// ---------------------------------------------------------------------------

extern "C" void kernel_launch(void* const* d_in, const int* in_sizes, int n_in,
                              void* d_out, int out_size, void* d_ws, size_t ws_size,
                              hipStream_t stream) {
    const float* x      = (const float*)d_in[0];
    const int*   o_edges= (const int*)d_in[1];
    const float* o_vals = (const float*)d_in[2];
    const int*   s_edges= (const int*)d_in[3];
    const float* s_vals = (const float*)d_in[4];
    const int*   idx    = (const int*)d_in[5];
    const float* W_o1   = (const float*)d_in[6];
    const float* b_o1   = (const float*)d_in[7];
    const float* W_o2   = (const float*)d_in[8];
    const float* b_o2   = (const float*)d_in[9];
    const float* W_s1   = (const float*)d_in[10];
    const float* b_s1   = (const float*)d_in[11];
    const float* W_s2   = (const float*)d_in[12];
    const float* b_s2   = (const float*)d_in[13];
    const float* ag1    = (const float*)d_in[14];
    const float* ag2    = (const float*)d_in[15];
    const float* dec1_W = (const float*)d_in[16];
    const float* dec1_b = (const float*)d_in[17];
    const float* dec2_W = (const float*)d_in[18];
    const float* dec2_b = (const float*)d_in[19];
    float* out = (float*)d_out;

    const int N = in_sizes[0] / 128;
    const int E = in_sizes[1] / 2;
    const int P = out_size;
    const int n2 = 2 * N;
    const int nb = (n2 + BKT_NODES - 1) / BKT_NODES;  // 782 for N=100k

    const size_t NBH = (size_t)N * 128 * 2;  // [N,128] bf16 bytes

    char* ws = (char*)d_ws;
    size_t off = 0;
    auto alloc = [&](size_t bytes) {
        char* p = ws + off;
        off += (bytes + 255) & ~(size_t)255;
        return p;
    };

    unsigned short* B0 = (unsigned short*)alloc(NBH);  // S1o (bf16)
    unsigned short* B1 = (unsigned short*)alloc(NBH);  // S1s (bf16)
    float4* To = (float4*)alloc((size_t)N * 16);
    float4* Ts = (float4*)alloc((size_t)N * 16);
    float* av = (float*)alloc((size_t)P * 4);
    float* bv = (float*)alloc((size_t)P * 4);
    float* Mo = (float*)alloc(3 * 128 * 4);
    float* Ms = (float*)alloc(3 * 128 * 4);
    float* beta = (float*)alloc(32);
    float* cc = (float*)alloc(16);
    int* bcnt  = (int*)alloc((size_t)nb * 4);
    int* bbase = (int*)alloc((size_t)(nb + 1) * 4);
    int* bcur  = (int*)alloc((size_t)nb * 4);
    int* rp2   = (int*)alloc((size_t)(n2 + 1) * 4);
    int2* binned = (int2*)alloc((size_t)2 * E * 8);
    int2* csr    = (int2*)alloc((size_t)2 * E * 8);

    const int nblk = (N + 255) / 256;

    // ---- CSR build: two-level bucket sort ----
    hipMemsetAsync(bcnt, 0, (size_t)nb * 4, stream);
    bhist_k<<<512, 256, 0, stream>>>(o_edges, s_edges, bcnt, E, N, nb);
    bscan_k<<<1, 1024, 0, stream>>>(bcnt, bbase, bcur, nb, 2 * E);
    const int chunk = 8192;
    bin_k<<<(2 * E + chunk - 1) / chunk, 256, 0, stream>>>(
        o_edges, o_vals, s_edges, s_vals, bcur, binned, E, N, nb, chunk);
    sort_k<<<nb, 256, 0, stream>>>(bbase, binned, csr, rp2, n2, 2 * E);

    // ---- projection precompute ----
    prep_k<<<1, 128, 0, stream>>>(dec1_W, dec1_b, dec2_W, dec2_b,
                                  W_o2, b_o2, W_s2, b_s2, ag1, ag2,
                                  Mo, Ms, beta, cc);

    // ---- layer 1 GEMMs (both branches, bf16 MFMA) ----
    dim3 ggrid((N + 127) / 128, 2);
    gemm_mfma_k<<<ggrid, 256, 0, stream>>>(x, W_o1, W_s1, B0, B1, N);

    // ---- layer-1 SpMM + bias + relu + projection to 3 scalars (both) ----
    dim3 sgrid((N * 64 + 255) / 256, 2);
    seg_spmm_fused2_k<<<sgrid, 256, 0, stream>>>(rp2, csr, B0, B1, b_o1, b_s1,
                                                 Mo, Ms, To, Ts, N);

    // ---- layer-2 scalar SpMM + gate ----
    gate_k<<<nblk, 256, 0, stream>>>(rp2, csr, To, Ts, beta, av, bv, N);

    decode_k<<<(P + 255) / 256, 256, 0, stream>>>(idx, av, bv, cc, out, P);
}